// Round 1
// baseline (3208.290 us; speedup 1.0000x reference)
//
#include <hip/hip_runtime.h>
#include <hip/hip_bf16.h>

#define INV_SQRT10 0.31622776601683794f
#define INV_SQRT64 0.125f
#define INV_SQRT32 0.17677669529663687f
#define INV_SQRT96 0.10206207261596575f
#define INV_SQRT3  0.5773502691896258f

// ---------------------------------------------------------------------------
// K1: node linear. wave-per-node. Computes (per layer input xs:(N,64), xv:(N,32,3)):
//   hs  = xs @ Wl1s * attr / sqrt(64)         (N,64)
//   hv  = einsum(xv, Wl1v) * attr / sqrt(32)  (N,32,3) stored (N,96) as k*3+i
//   scs = xs @ Wscs * attr / sqrt(64)         (N,OS)
//   scv = einsum(xv, Wscv) * attr / sqrt(32)  (N,32,3)
// ---------------------------------------------------------------------------
template <int OS>
__global__ __launch_bounds__(256) void k_node_lin(
    const float* __restrict__ xs, const float* __restrict__ xv,
    const float* __restrict__ attr,
    const float* __restrict__ Wl1s, const float* __restrict__ Wl1v,
    const float* __restrict__ Wscs, const float* __restrict__ Wscv,
    float* __restrict__ hs, float* __restrict__ hv,
    float* __restrict__ scs, float* __restrict__ scv, int N)
{
    __shared__ float xs_l[4][64];
    __shared__ float xv_l[4][96];
    const int wave = threadIdx.x >> 6, lane = threadIdx.x & 63;
    const int n = blockIdx.x * 4 + wave;
    const bool valid = n < N;
    float a = 0.f;
    if (valid) {
        xs_l[wave][lane] = xs[(size_t)n * 64 + lane];
        xv_l[wave][lane] = xv[(size_t)n * 96 + lane];
        if (lane < 32) xv_l[wave][64 + lane] = xv[(size_t)n * 96 + 64 + lane];
        a = attr[n];
    }
    __syncthreads();
    if (valid) {
        // scalar dots
        float acc_h = 0.f, acc_s0 = 0.f, acc_s1 = 0.f;
        const int laneB = lane & 31;
        #pragma unroll 8
        for (int k = 0; k < 64; k++) {
            float x = xs_l[wave][k];
            acc_h  += x * Wl1s[k * 64 + lane];
            acc_s0 += x * Wscs[k * OS + lane];
            if (OS == 96) acc_s1 += x * Wscs[k * 96 + 64 + laneB];
        }
        hs[(size_t)n * 64 + lane] = acc_h * INV_SQRT64 * a;
        scs[(size_t)n * OS + lane] = acc_s0 * INV_SQRT64 * a;
        if (OS == 96 && lane < 32) scs[(size_t)n * 96 + 64 + lane] = acc_s1 * INV_SQRT64 * a;
        // vector dots: slot p = k*3+i; lane handles p=lane, and p2=64+lane for lane<32
        const int k1 = lane / 3, i1 = lane - k1 * 3;
        const int p2 = (lane < 32) ? (64 + lane) : 95;
        const int k2 = p2 / 3, i2 = p2 - k2 * 3;
        float ah1 = 0.f, as1 = 0.f, ah2 = 0.f, as2 = 0.f;
        #pragma unroll 8
        for (int u = 0; u < 32; u++) {
            float x1 = xv_l[wave][u * 3 + i1];
            float x2 = xv_l[wave][u * 3 + i2];
            ah1 += x1 * Wl1v[u * 32 + k1];
            as1 += x1 * Wscv[u * 32 + k1];
            ah2 += x2 * Wl1v[u * 32 + k2];
            as2 += x2 * Wscv[u * 32 + k2];
        }
        hv[(size_t)n * 96 + lane] = ah1 * INV_SQRT32 * a;
        scv[(size_t)n * 96 + lane] = as1 * INV_SQRT32 * a;
        if (lane < 32) {
            hv[(size_t)n * 96 + 64 + lane] = ah2 * INV_SQRT32 * a;
            scv[(size_t)n * 96 + 64 + lane] = as2 * INV_SQRT32 * a;
        }
    }
}

// ---------------------------------------------------------------------------
// K2: fused edge MLP + message + atomic scatter. wave-per-edge (strided).
//   h = silu(esc @ Wfc1 / sqrt(10))                (64)
//   w = h @ Wfc2 / sqrt(64)  -> w1|w2|w3|w4 (64|64|32|32)
//   m_s[0:64]  = gs*sh0*w1 ; m_s[64:96] = (gv.shv)/sqrt3 * w4
//   m_v[u<64][i] = gs[u]*shv[i]*w2[u] ; m_v[64+u][i] = gv[u][i]*sh0*w3[u]
//   atomicAdd into Ms (N,96), Mv (N,96,3), deg (N)
// ---------------------------------------------------------------------------
__global__ __launch_bounds__(256) void k_edge(
    const float* __restrict__ hs, const float* __restrict__ hv,
    const int* __restrict__ src, const int* __restrict__ dst,
    const float* __restrict__ sh, const float* __restrict__ esc,
    const float* __restrict__ Wfc1, const float* __restrict__ Wfc2,
    float* __restrict__ Ms, float* __restrict__ Mv, float* __restrict__ deg, int E)
{
    __shared__ float w1_l[640];        // 10 x 64
    __shared__ float w2_l[64 * 192];   // 64 x 192
    for (int i = threadIdx.x; i < 640; i += 256) w1_l[i] = Wfc1[i];
    for (int i = threadIdx.x; i < 64 * 192; i += 256) w2_l[i] = Wfc2[i];
    __syncthreads();

    const int lane = threadIdx.x & 63;
    const int gw = blockIdx.x * 4 + (threadIdx.x >> 6);
    const int nw = gridDim.x * 4;
    const int colB = (lane < 32) ? (128 + lane) : (160 + lane - 32);

    for (int e = gw; e < E; e += nw) {
        const int s = src[e], d = dst[e];
        // ---- h = silu(esc @ Wfc1 / sqrt(10)) : lane k computes h[k]
        float acc = 0.f;
        #pragma unroll
        for (int j = 0; j < 10; j++) acc += esc[(size_t)e * 10 + j] * w1_l[j * 64 + lane];
        acc *= INV_SQRT10;
        const float h = acc / (1.f + __expf(-acc));
        // ---- w dots: lane computes w1[lane], w2[lane], and w3/w4 half
        float w1 = 0.f, w2 = 0.f, wB = 0.f;
        #pragma unroll 8
        for (int k = 0; k < 64; k++) {
            float hk = __shfl(h, k);
            w1 += hk * w2_l[k * 192 + lane];
            w2 += hk * w2_l[k * 192 + 64 + lane];
            wB += hk * w2_l[k * 192 + colB];
        }
        w1 *= INV_SQRT64; w2 *= INV_SQRT64; wB *= INV_SQRT64;
        // ---- gather source node features
        const float gs = hs[(size_t)s * 64 + lane];
        float gv0 = 0.f, gv1 = 0.f, gv2 = 0.f;
        if (lane < 32) {
            gv0 = hv[(size_t)s * 96 + lane * 3 + 0];
            gv1 = hv[(size_t)s * 96 + lane * 3 + 1];
            gv2 = hv[(size_t)s * 96 + lane * 3 + 2];
        }
        const float sh0 = sh[(size_t)e * 4 + 0];
        const float sv1 = sh[(size_t)e * 4 + 1];
        const float sv2 = sh[(size_t)e * 4 + 2];
        const float sv3 = sh[(size_t)e * 4 + 3];
        const float gvdot = gv0 * sv1 + gv1 * sv2 + gv2 * sv3;
        const float gvd = __shfl(gvdot, lane & 31);   // lane 32+j gets lane j's dot
        // ---- scatter
        float* Msd = Ms + (size_t)d * 96;
        float* Mvd = Mv + (size_t)d * 288;
        atomicAdd(Msd + lane, gs * sh0 * w1);
        if (lane >= 32) atomicAdd(Msd + 64 + (lane - 32), gvd * INV_SQRT3 * wB);
        atomicAdd(Mvd + lane * 3 + 0, gs * sv1 * w2);
        atomicAdd(Mvd + lane * 3 + 1, gs * sv2 * w2);
        atomicAdd(Mvd + lane * 3 + 2, gs * sv3 * w2);
        if (lane < 32) {
            atomicAdd(Mvd + (64 + lane) * 3 + 0, gv0 * sh0 * wB);
            atomicAdd(Mvd + (64 + lane) * 3 + 1, gv1 * sh0 * wB);
            atomicAdd(Mvd + (64 + lane) * 3 + 2, gv2 * sh0 * wB);
        }
        if (lane == 0) atomicAdd(deg + d, 1.0f);
    }
}

// ---------------------------------------------------------------------------
// K3: node finalize. wave-per-node.
//   Msn = Ms/deg ; Mvn = Mv/deg
//   alpha = (Msn @ Wa)/sqrt(96)*attr
//   os = Msn @ W2s /sqrt(96)*attr ; ov = einsum(Mvn,W2v)/sqrt(96)*attr
//   s = scs + alpha*os ; v = scv + alpha*ov
//   FINAL=false (layer1): write gs=silu(s[:64]) and vg=v*sigmoid(s[64:96])
//   FINAL=true  (layer2): write d_out[n][0:64]=s, [64+k*3+i]=v
// ---------------------------------------------------------------------------
template <int OS, bool FINAL>
__global__ __launch_bounds__(256) void k_node_out(
    const float* __restrict__ Ms, const float* __restrict__ Mv,
    const float* __restrict__ deg, const float* __restrict__ attr,
    const float* __restrict__ scs, const float* __restrict__ scv,
    const float* __restrict__ W2s, const float* __restrict__ W2v,
    const float* __restrict__ Wa,
    float* __restrict__ outS, float* __restrict__ outV, int N)
{
    __shared__ float ms_l[4][96];
    __shared__ float mv_l[4][288];
    __shared__ float gate_l[4][32];
    const int wave = threadIdx.x >> 6, lane = threadIdx.x & 63;
    const int n = blockIdx.x * 4 + wave;
    const bool valid = n < N;
    float a = 0.f;
    if (valid) {
        const float invd = 1.f / fmaxf(deg[n], 1.f);
        a = attr[n];
        ms_l[wave][lane] = Ms[(size_t)n * 96 + lane] * invd;
        if (lane < 32) ms_l[wave][64 + lane] = Ms[(size_t)n * 96 + 64 + lane] * invd;
        for (int t = lane; t < 288; t += 64) mv_l[wave][t] = Mv[(size_t)n * 288 + t] * invd;
    }
    __syncthreads();
    float sA = 0.f, sB = 0.f, vA = 0.f, vB = 0.f;
    if (valid) {
        // alpha (full-wave reduce)
        float p = ms_l[wave][lane] * Wa[lane];
        if (lane < 32) p += ms_l[wave][64 + lane] * Wa[64 + lane];
        #pragma unroll
        for (int o = 32; o > 0; o >>= 1) p += __shfl_xor(p, o);
        const float alpha = p * INV_SQRT96 * a;
        // scalar outputs: c=lane (and c=64+lane for lane<32 when OS==96)
        const int laneB = lane & 31;
        float acc0 = 0.f, acc1 = 0.f;
        #pragma unroll 8
        for (int j = 0; j < 96; j++) {
            float m = ms_l[wave][j];
            acc0 += m * W2s[j * OS + lane];
            if (OS == 96) acc1 += m * W2s[j * 96 + 64 + laneB];
        }
        sA = scs[(size_t)n * OS + lane] + alpha * (acc0 * INV_SQRT96 * a);
        if (OS == 96) sB = scs[(size_t)n * 96 + 64 + laneB] + alpha * (acc1 * INV_SQRT96 * a);
        // vector outputs: slot p=lane, p2=64+lane (lane<32)
        const int k1 = lane / 3, i1 = lane - k1 * 3;
        const int p2 = (lane < 32) ? (64 + lane) : 95;
        const int k2 = p2 / 3, i2 = p2 - k2 * 3;
        float av0 = 0.f, av1 = 0.f;
        #pragma unroll 8
        for (int j = 0; j < 96; j++) {
            av0 += mv_l[wave][j * 3 + i1] * W2v[j * 32 + k1];
            av1 += mv_l[wave][j * 3 + i2] * W2v[j * 32 + k2];
        }
        vA = scv[(size_t)n * 96 + lane] + alpha * (av0 * INV_SQRT96 * a);
        vB = scv[(size_t)n * 96 + p2] + alpha * (av1 * INV_SQRT96 * a);
    }
    if (!FINAL) {
        if (valid && lane < 32) gate_l[wave][lane] = 1.f / (1.f + __expf(-sB));
    }
    __syncthreads();
    if (valid) {
        if (FINAL) {
            float* o = outS + (size_t)n * 160;
            o[lane] = sA;                    // OS==64: s2
            o[64 + lane] = vA;               // v2 slots 0..63
            if (lane < 32) o[128 + lane] = vB;  // v2 slots 64..95
        } else {
            outS[(size_t)n * 64 + lane] = sA / (1.f + __expf(-sA));  // silu(s[:64])
            const int k1 = lane / 3;
            outV[(size_t)n * 96 + lane] = vA * gate_l[wave][k1];
            if (lane < 32) {
                const int k2 = (64 + lane) / 3;
                outV[(size_t)n * 96 + 64 + lane] = vB * gate_l[wave][k2];
            }
        }
    }
}

// ---------------------------------------------------------------------------
extern "C" void kernel_launch(void* const* d_in, const int* in_sizes, int n_in,
                              void* d_out, int out_size, void* d_ws, size_t ws_size,
                              hipStream_t stream)
{
    const float* node_s = (const float*)d_in[0];
    const float* node_v = (const float*)d_in[1];
    const float* attr   = (const float*)d_in[2];
    const int*   esrc   = (const int*)d_in[3];
    const int*   edst   = (const int*)d_in[4];
    const float* esh    = (const float*)d_in[5];
    const float* esc    = (const float*)d_in[6];
    const float* W[18];
    for (int i = 0; i < 18; i++) W[i] = (const float*)d_in[7 + i];
    // per layer: 0 sc_s, 1 sc_v, 2 lin1_s, 3 lin1_v, 4 fc1, 5 fc2, 6 lin2_s, 7 lin2_v, 8 alpha

    const int N = in_sizes[0] / 64;
    const int E = in_sizes[3];

    float* ws  = (float*)d_ws;
    float* hs  = ws;                          // N*64
    float* hvb = hs  + (size_t)N * 64;        // N*96
    float* scs = hvb + (size_t)N * 96;        // N*96
    float* scv = scs + (size_t)N * 96;        // N*96
    float* Ms  = scv + (size_t)N * 96;        // N*96
    float* Mv  = Ms  + (size_t)N * 96;        // N*288
    float* dg  = Mv  + (size_t)N * 288;       // N
    float* gsb = dg  + (size_t)N;             // N*64
    float* vgb = gsb + (size_t)N * 64;        // N*96

    const int nb = (N + 3) / 4;
    const int eb = 2048;

    // ---- layer 1
    hipMemsetAsync(Ms, 0, (size_t)N * 385 * sizeof(float), stream);  // Ms|Mv|deg contiguous
    k_node_lin<96><<<nb, 256, 0, stream>>>(node_s, node_v, attr, W[2], W[3], W[0], W[1],
                                           hs, hvb, scs, scv, N);
    k_edge<<<eb, 256, 0, stream>>>(hs, hvb, esrc, edst, esh, esc, W[4], W[5], Ms, Mv, dg, E);
    k_node_out<96, false><<<nb, 256, 0, stream>>>(Ms, Mv, dg, attr, scs, scv,
                                                  W[6], W[7], W[8], gsb, vgb, N);
    // ---- layer 2
    hipMemsetAsync(Ms, 0, (size_t)N * 385 * sizeof(float), stream);
    k_node_lin<64><<<nb, 256, 0, stream>>>(gsb, vgb, attr, W[11], W[12], W[9], W[10],
                                           hs, hvb, scs, scv, N);
    k_edge<<<eb, 256, 0, stream>>>(hs, hvb, esrc, edst, esh, esc, W[13], W[14], Ms, Mv, dg, E);
    k_node_out<64, true><<<nb, 256, 0, stream>>>(Ms, Mv, dg, attr, scs, scv,
                                                 W[15], W[16], W[17], (float*)d_out, nullptr, N);
}

// Round 2
// 1994.650 us; speedup vs baseline: 1.6084x; 1.6084x over previous
//
#include <hip/hip_runtime.h>
#include <hip/hip_bf16.h>

#define INV_SQRT10 0.31622776601683794f
#define INV_SQRT64 0.125f
#define INV_SQRT32 0.17677669529663687f
#define INV_SQRT96 0.10206207261596575f
#define INV_SQRT3  0.5773502691896258f

// ---------------------------------------------------------------------------
// K1: node linear. wave-per-node.
// ---------------------------------------------------------------------------
template <int OS>
__global__ __launch_bounds__(256) void k_node_lin(
    const float* __restrict__ xs, const float* __restrict__ xv,
    const float* __restrict__ attr,
    const float* __restrict__ Wl1s, const float* __restrict__ Wl1v,
    const float* __restrict__ Wscs, const float* __restrict__ Wscv,
    float* __restrict__ hs, float* __restrict__ hv,
    float* __restrict__ scs, float* __restrict__ scv, int N)
{
    __shared__ float xs_l[4][64];
    __shared__ float xv_l[4][96];
    const int wave = threadIdx.x >> 6, lane = threadIdx.x & 63;
    const int n = blockIdx.x * 4 + wave;
    const bool valid = n < N;
    float a = 0.f;
    if (valid) {
        xs_l[wave][lane] = xs[(size_t)n * 64 + lane];
        xv_l[wave][lane] = xv[(size_t)n * 96 + lane];
        if (lane < 32) xv_l[wave][64 + lane] = xv[(size_t)n * 96 + 64 + lane];
        a = attr[n];
    }
    __syncthreads();
    if (valid) {
        float acc_h = 0.f, acc_s0 = 0.f, acc_s1 = 0.f;
        const int laneB = lane & 31;
        #pragma unroll 8
        for (int k = 0; k < 64; k++) {
            float x = xs_l[wave][k];
            acc_h  += x * Wl1s[k * 64 + lane];
            acc_s0 += x * Wscs[k * OS + lane];
            if (OS == 96) acc_s1 += x * Wscs[k * 96 + 64 + laneB];
        }
        hs[(size_t)n * 64 + lane] = acc_h * INV_SQRT64 * a;
        scs[(size_t)n * OS + lane] = acc_s0 * INV_SQRT64 * a;
        if (OS == 96 && lane < 32) scs[(size_t)n * 96 + 64 + lane] = acc_s1 * INV_SQRT64 * a;
        const int k1 = lane / 3, i1 = lane - k1 * 3;
        const int p2 = (lane < 32) ? (64 + lane) : 95;
        const int k2 = p2 / 3, i2 = p2 - k2 * 3;
        float ah1 = 0.f, as1 = 0.f, ah2 = 0.f, as2 = 0.f;
        #pragma unroll 8
        for (int u = 0; u < 32; u++) {
            float x1 = xv_l[wave][u * 3 + i1];
            float x2 = xv_l[wave][u * 3 + i2];
            ah1 += x1 * Wl1v[u * 32 + k1];
            as1 += x1 * Wscv[u * 32 + k1];
            ah2 += x2 * Wl1v[u * 32 + k2];
            as2 += x2 * Wscv[u * 32 + k2];
        }
        hv[(size_t)n * 96 + lane] = ah1 * INV_SQRT32 * a;
        scv[(size_t)n * 96 + lane] = as1 * INV_SQRT32 * a;
        if (lane < 32) {
            hv[(size_t)n * 96 + 64 + lane] = ah2 * INV_SQRT32 * a;
            scv[(size_t)n * 96 + 64 + lane] = as2 * INV_SQRT32 * a;
        }
    }
}

// ---------------------------------------------------------------------------
// CSR build: count -> scan -> scatter. Same graph both layers; built once.
// ---------------------------------------------------------------------------
__global__ __launch_bounds__(256) void k_count(const int* __restrict__ dst,
                                               int* __restrict__ cnt, int E)
{
    int i = blockIdx.x * 256 + threadIdx.x;
    if (i < E) atomicAdd(&cnt[dst[i]], 1);
}

__global__ __launch_bounds__(1024) void k_scan(const int* __restrict__ cnt,
                                               int* __restrict__ base, int N)
{
    __shared__ int lds[1024];
    const int t = threadIdx.x;
    const int chunk = (N + 1023) / 1024;
    const int s = t * chunk, e = min(s + chunk, N);
    int local = 0;
    for (int i = s; i < e; i++) local += cnt[i];
    lds[t] = local;
    __syncthreads();
    for (int off = 1; off < 1024; off <<= 1) {
        int v = (t >= off) ? lds[t - off] : 0;
        __syncthreads();
        lds[t] += v;
        __syncthreads();
    }
    int running = lds[t] - local;  // exclusive prefix
    for (int i = s; i < e; i++) { base[i] = running; running += cnt[i]; }
}

__global__ __launch_bounds__(256) void k_scatter(const int* __restrict__ dst,
                                                 const int* __restrict__ base,
                                                 int* __restrict__ cursor,
                                                 int* __restrict__ order, int E)
{
    int i = blockIdx.x * 256 + threadIdx.x;
    if (i < E) {
        const int d = dst[i];
        const int p = atomicAdd(&cursor[d], 1);
        order[base[d] + p] = i;
    }
}

// ---------------------------------------------------------------------------
// K2': aggregation, wave-per-dst-node over CSR edge list. No atomics.
//   per edge: h = silu(esc@Wfc1/sqrt10); w = h@Wfc2/sqrt64 -> w1|w2|w3|w4
//   accumulate m_s(96) + m_v(288) in registers, write once.
// ---------------------------------------------------------------------------
__global__ __launch_bounds__(256) void k_agg(
    const float* __restrict__ hs, const float* __restrict__ hv,
    const int* __restrict__ src, const float* __restrict__ sh,
    const float* __restrict__ esc,
    const int* __restrict__ order, const int* __restrict__ base,
    const int* __restrict__ cnt,
    const float* __restrict__ Wfc1, const float* __restrict__ Wfc2,
    float* __restrict__ Ms, float* __restrict__ Mv, int N)
{
    __shared__ float w1_l[640];        // 10 x 64
    __shared__ float w2_l[64 * 192];   // 64 x 192
    for (int i = threadIdx.x; i < 640; i += 256) w1_l[i] = Wfc1[i];
    for (int i = threadIdx.x; i < 64 * 192; i += 256) w2_l[i] = Wfc2[i];
    __syncthreads();

    const int wave = threadIdx.x >> 6, lane = threadIdx.x & 63;
    const int n = blockIdx.x * 4 + wave;
    if (n >= N) return;
    const int b0 = base[n], c = cnt[n];
    const int colB = (lane < 32) ? (128 + lane) : (160 + lane - 32);

    float aS = 0.f, aSB = 0.f;
    float aV0 = 0.f, aV1 = 0.f, aV2 = 0.f;
    float aB0 = 0.f, aB1 = 0.f, aB2 = 0.f;

    for (int j = 0; j < c; ++j) {
        const int e = order[b0 + j];
        const int s = src[e];
        // edge MLP layer 1: lane k holds h[k]
        float acc = 0.f;
        #pragma unroll
        for (int q = 0; q < 10; q++) acc += esc[(size_t)e * 10 + q] * w1_l[q * 64 + lane];
        acc *= INV_SQRT10;
        const float h = acc / (1.f + __expf(-acc));
        // edge MLP layer 2: lane computes cols {lane, 64+lane, colB}
        float w1 = 0.f, w2 = 0.f, wB = 0.f;
        #pragma unroll 8
        for (int k = 0; k < 64; k++) {
            const float hk = __shfl(h, k);
            w1 += hk * w2_l[k * 192 + lane];
            w2 += hk * w2_l[k * 192 + 64 + lane];
            wB += hk * w2_l[k * 192 + colB];
        }
        w1 *= INV_SQRT64; w2 *= INV_SQRT64; wB *= INV_SQRT64;
        // gather source features
        const float gs = hs[(size_t)s * 64 + lane];
        float gv0 = 0.f, gv1 = 0.f, gv2 = 0.f;
        if (lane < 32) {
            gv0 = hv[(size_t)s * 96 + lane * 3 + 0];
            gv1 = hv[(size_t)s * 96 + lane * 3 + 1];
            gv2 = hv[(size_t)s * 96 + lane * 3 + 2];
        }
        const float sh0 = sh[(size_t)e * 4 + 0];
        const float sv1 = sh[(size_t)e * 4 + 1];
        const float sv2 = sh[(size_t)e * 4 + 2];
        const float sv3 = sh[(size_t)e * 4 + 3];
        const float gvdot = gv0 * sv1 + gv1 * sv2 + gv2 * sv3;
        const float gvd = __shfl(gvdot, lane & 31);  // lanes 32+j get lane j's dot
        // accumulate message slots owned by this lane
        aS  += gs * sh0 * w1;
        aSB += gvd * INV_SQRT3 * wB;      // used by lanes >= 32
        aV0 += gs * sv1 * w2;
        aV1 += gs * sv2 * w2;
        aV2 += gs * sv3 * w2;
        aB0 += gv0 * sh0 * wB;            // used by lanes < 32
        aB1 += gv1 * sh0 * wB;
        aB2 += gv2 * sh0 * wB;
    }
    float* Msd = Ms + (size_t)n * 96;
    float* Mvd = Mv + (size_t)n * 288;
    Msd[lane] = aS;
    if (lane >= 32) Msd[64 + (lane - 32)] = aSB;
    Mvd[lane * 3 + 0] = aV0;
    Mvd[lane * 3 + 1] = aV1;
    Mvd[lane * 3 + 2] = aV2;
    if (lane < 32) {
        Mvd[(64 + lane) * 3 + 0] = aB0;
        Mvd[(64 + lane) * 3 + 1] = aB1;
        Mvd[(64 + lane) * 3 + 2] = aB2;
    }
}

// ---------------------------------------------------------------------------
// K3: node finalize. wave-per-node. deg comes from CSR counts.
// ---------------------------------------------------------------------------
template <int OS, bool FINAL>
__global__ __launch_bounds__(256) void k_node_out(
    const float* __restrict__ Ms, const float* __restrict__ Mv,
    const int* __restrict__ cnt, const float* __restrict__ attr,
    const float* __restrict__ scs, const float* __restrict__ scv,
    const float* __restrict__ W2s, const float* __restrict__ W2v,
    const float* __restrict__ Wa,
    float* __restrict__ outS, float* __restrict__ outV, int N)
{
    __shared__ float ms_l[4][96];
    __shared__ float mv_l[4][288];
    __shared__ float gate_l[4][32];
    const int wave = threadIdx.x >> 6, lane = threadIdx.x & 63;
    const int n = blockIdx.x * 4 + wave;
    const bool valid = n < N;
    float a = 0.f;
    if (valid) {
        const float invd = 1.f / (float)max(cnt[n], 1);
        a = attr[n];
        ms_l[wave][lane] = Ms[(size_t)n * 96 + lane] * invd;
        if (lane < 32) ms_l[wave][64 + lane] = Ms[(size_t)n * 96 + 64 + lane] * invd;
        for (int t = lane; t < 288; t += 64) mv_l[wave][t] = Mv[(size_t)n * 288 + t] * invd;
    }
    __syncthreads();
    float sA = 0.f, sB = 0.f, vA = 0.f, vB = 0.f;
    if (valid) {
        float p = ms_l[wave][lane] * Wa[lane];
        if (lane < 32) p += ms_l[wave][64 + lane] * Wa[64 + lane];
        #pragma unroll
        for (int o = 32; o > 0; o >>= 1) p += __shfl_xor(p, o);
        const float alpha = p * INV_SQRT96 * a;
        const int laneB = lane & 31;
        float acc0 = 0.f, acc1 = 0.f;
        #pragma unroll 8
        for (int j = 0; j < 96; j++) {
            float m = ms_l[wave][j];
            acc0 += m * W2s[j * OS + lane];
            if (OS == 96) acc1 += m * W2s[j * 96 + 64 + laneB];
        }
        sA = scs[(size_t)n * OS + lane] + alpha * (acc0 * INV_SQRT96 * a);
        if (OS == 96) sB = scs[(size_t)n * 96 + 64 + laneB] + alpha * (acc1 * INV_SQRT96 * a);
        const int k1 = lane / 3, i1 = lane - k1 * 3;
        const int p2 = (lane < 32) ? (64 + lane) : 95;
        const int k2 = p2 / 3, i2 = p2 - k2 * 3;
        float av0 = 0.f, av1 = 0.f;
        #pragma unroll 8
        for (int j = 0; j < 96; j++) {
            av0 += mv_l[wave][j * 3 + i1] * W2v[j * 32 + k1];
            av1 += mv_l[wave][j * 3 + i2] * W2v[j * 32 + k2];
        }
        vA = scv[(size_t)n * 96 + lane] + alpha * (av0 * INV_SQRT96 * a);
        vB = scv[(size_t)n * 96 + p2] + alpha * (av1 * INV_SQRT96 * a);
    }
    if (!FINAL) {
        if (valid && lane < 32) gate_l[wave][lane] = 1.f / (1.f + __expf(-sB));
    }
    __syncthreads();
    if (valid) {
        if (FINAL) {
            float* o = outS + (size_t)n * 160;
            o[lane] = sA;
            o[64 + lane] = vA;
            if (lane < 32) o[128 + lane] = vB;
        } else {
            outS[(size_t)n * 64 + lane] = sA / (1.f + __expf(-sA));
            const int k1 = lane / 3;
            outV[(size_t)n * 96 + lane] = vA * gate_l[wave][k1];
            if (lane < 32) {
                const int k2 = (64 + lane) / 3;
                outV[(size_t)n * 96 + 64 + lane] = vB * gate_l[wave][k2];
            }
        }
    }
}

// ---------------------------------------------------------------------------
extern "C" void kernel_launch(void* const* d_in, const int* in_sizes, int n_in,
                              void* d_out, int out_size, void* d_ws, size_t ws_size,
                              hipStream_t stream)
{
    const float* node_s = (const float*)d_in[0];
    const float* node_v = (const float*)d_in[1];
    const float* attr   = (const float*)d_in[2];
    const int*   esrc   = (const int*)d_in[3];
    const int*   edst   = (const int*)d_in[4];
    const float* esh    = (const float*)d_in[5];
    const float* esc    = (const float*)d_in[6];
    const float* W[18];
    for (int i = 0; i < 18; i++) W[i] = (const float*)d_in[7 + i];
    // per layer: 0 sc_s, 1 sc_v, 2 lin1_s, 3 lin1_v, 4 fc1, 5 fc2, 6 lin2_s, 7 lin2_v, 8 alpha

    const int N = in_sizes[0] / 64;
    const int E = in_sizes[3];

    float* ws  = (float*)d_ws;
    float* hs  = ws;                          // N*64
    float* hvb = hs  + (size_t)N * 64;        // N*96
    float* scs = hvb + (size_t)N * 96;        // N*96
    float* scv = scs + (size_t)N * 96;        // N*96
    float* Ms  = scv + (size_t)N * 96;        // N*96
    float* Mv  = Ms  + (size_t)N * 96;        // N*288
    float* gsb = Mv  + (size_t)N * 288;       // N*64
    float* vgb = gsb + (size_t)N * 64;        // N*96
    int*   cnt    = (int*)(vgb + (size_t)N * 96);  // N
    int*   cursor = cnt + N;                        // N  (adjacent to cnt: one memset)
    int*   basei  = cursor + N;                     // N
    int*   order  = basei + N;                      // E

    const int nb = (N + 3) / 4;
    const int ebk = (E + 255) / 256;

    // ---- CSR build (graph identical for both layers)
    hipMemsetAsync(cnt, 0, (size_t)2 * N * sizeof(int), stream);  // cnt + cursor
    k_count<<<ebk, 256, 0, stream>>>(edst, cnt, E);
    k_scan<<<1, 1024, 0, stream>>>(cnt, basei, N);
    k_scatter<<<ebk, 256, 0, stream>>>(edst, basei, cursor, order, E);

    // ---- layer 1
    k_node_lin<96><<<nb, 256, 0, stream>>>(node_s, node_v, attr, W[2], W[3], W[0], W[1],
                                           hs, hvb, scs, scv, N);
    k_agg<<<nb, 256, 0, stream>>>(hs, hvb, esrc, esh, esc, order, basei, cnt,
                                  W[4], W[5], Ms, Mv, N);
    k_node_out<96, false><<<nb, 256, 0, stream>>>(Ms, Mv, cnt, attr, scs, scv,
                                                  W[6], W[7], W[8], gsb, vgb, N);
    // ---- layer 2
    k_node_lin<64><<<nb, 256, 0, stream>>>(gsb, vgb, attr, W[11], W[12], W[9], W[10],
                                           hs, hvb, scs, scv, N);
    k_agg<<<nb, 256, 0, stream>>>(hs, hvb, esrc, esh, esc, order, basei, cnt,
                                  W[13], W[14], Ms, Mv, N);
    k_node_out<64, true><<<nb, 256, 0, stream>>>(Ms, Mv, cnt, attr, scs, scv,
                                                 W[15], W[16], W[17], (float*)d_out, nullptr, N);
}

// Round 3
// 1164.640 us; speedup vs baseline: 2.7547x; 1.7127x over previous
//
#include <hip/hip_runtime.h>
#include <hip/hip_bf16.h>

#define INV_SQRT10 0.31622776601683794f
#define INV_SQRT64 0.125f
#define INV_SQRT32 0.17677669529663687f
#define INV_SQRT96 0.10206207261596575f
#define INV_SQRT3  0.5773502691896258f

typedef __attribute__((ext_vector_type(4))) float f32x4;
typedef __attribute__((ext_vector_type(8))) short bf16x8;

__device__ __forceinline__ unsigned short f2bf(float x) {
    union { float f; unsigned u; } v; v.f = x;
    unsigned r = v.u + 0x7FFF + ((v.u >> 16) & 1);
    return (unsigned short)(r >> 16);
}
__device__ __forceinline__ float bf2f(unsigned short u) {
    union { unsigned u; float f; } v; v.u = ((unsigned)u) << 16;
    return v.f;
}

// ---------------------------------------------------------------------------
// K1: node linear. wave-per-node. (weight streams split so each k-loop's
// working set fits 32KB L1: Wl1s 16KB, then Wscs <=24KB)
// ---------------------------------------------------------------------------
template <int OS>
__global__ __launch_bounds__(256) void k_node_lin(
    const float* __restrict__ xs, const float* __restrict__ xv,
    const float* __restrict__ attr,
    const float* __restrict__ Wl1s, const float* __restrict__ Wl1v,
    const float* __restrict__ Wscs, const float* __restrict__ Wscv,
    float* __restrict__ hs, float* __restrict__ hv,
    float* __restrict__ scs, float* __restrict__ scv, int N)
{
    __shared__ float xs_l[4][64];
    __shared__ float xv_l[4][96];
    const int wave = threadIdx.x >> 6, lane = threadIdx.x & 63;
    const int n = blockIdx.x * 4 + wave;
    const bool valid = n < N;
    float a = 0.f;
    if (valid) {
        xs_l[wave][lane] = xs[(size_t)n * 64 + lane];
        xv_l[wave][lane] = xv[(size_t)n * 96 + lane];
        if (lane < 32) xv_l[wave][64 + lane] = xv[(size_t)n * 96 + 64 + lane];
        a = attr[n];
    }
    __syncthreads();
    if (valid) {
        const int laneB = lane & 31;
        float acc_h = 0.f;
        #pragma unroll 8
        for (int k = 0; k < 64; k++) acc_h += xs_l[wave][k] * Wl1s[k * 64 + lane];
        hs[(size_t)n * 64 + lane] = acc_h * INV_SQRT64 * a;
        float acc_s0 = 0.f, acc_s1 = 0.f;
        #pragma unroll 8
        for (int k = 0; k < 64; k++) {
            float x = xs_l[wave][k];
            acc_s0 += x * Wscs[k * OS + lane];
            if (OS == 96) acc_s1 += x * Wscs[k * 96 + 64 + laneB];
        }
        scs[(size_t)n * OS + lane] = acc_s0 * INV_SQRT64 * a;
        if (OS == 96 && lane < 32) scs[(size_t)n * 96 + 64 + lane] = acc_s1 * INV_SQRT64 * a;
        const int k1 = lane / 3, i1 = lane - k1 * 3;
        const int p2 = (lane < 32) ? (64 + lane) : 95;
        const int k2 = p2 / 3, i2 = p2 - k2 * 3;
        float ah1 = 0.f, as1 = 0.f, ah2 = 0.f, as2 = 0.f;
        #pragma unroll 8
        for (int u = 0; u < 32; u++) {
            float x1 = xv_l[wave][u * 3 + i1];
            float x2 = xv_l[wave][u * 3 + i2];
            ah1 += x1 * Wl1v[u * 32 + k1];
            as1 += x1 * Wscv[u * 32 + k1];
            ah2 += x2 * Wl1v[u * 32 + k2];
            as2 += x2 * Wscv[u * 32 + k2];
        }
        hv[(size_t)n * 96 + lane] = ah1 * INV_SQRT32 * a;
        scv[(size_t)n * 96 + lane] = as1 * INV_SQRT32 * a;
        if (lane < 32) {
            hv[(size_t)n * 96 + 64 + lane] = ah2 * INV_SQRT32 * a;
            scv[(size_t)n * 96 + 64 + lane] = as2 * INV_SQRT32 * a;
        }
    }
}

// ---------------------------------------------------------------------------
// CSR build: count -> scan -> scatter. Same graph both layers; built once.
// ---------------------------------------------------------------------------
__global__ __launch_bounds__(256) void k_count(const int* __restrict__ dst,
                                               int* __restrict__ cnt, int E)
{
    int i = blockIdx.x * 256 + threadIdx.x;
    if (i < E) atomicAdd(&cnt[dst[i]], 1);
}

__global__ __launch_bounds__(1024) void k_scan(const int* __restrict__ cnt,
                                               int* __restrict__ base, int N)
{
    __shared__ int lds[1024];
    const int t = threadIdx.x;
    const int chunk = (N + 1023) / 1024;
    const int s = t * chunk, e = min(s + chunk, N);
    int local = 0;
    for (int i = s; i < e; i++) local += cnt[i];
    lds[t] = local;
    __syncthreads();
    for (int off = 1; off < 1024; off <<= 1) {
        int v = (t >= off) ? lds[t - off] : 0;
        __syncthreads();
        lds[t] += v;
        __syncthreads();
    }
    int running = lds[t] - local;  // exclusive prefix
    for (int i = s; i < e; i++) { base[i] = running; running += cnt[i]; }
}

__global__ __launch_bounds__(256) void k_scatter(const int* __restrict__ dst,
                                                 const int* __restrict__ base,
                                                 int* __restrict__ cursor,
                                                 int* __restrict__ order, int E)
{
    int i = blockIdx.x * 256 + threadIdx.x;
    if (i < E) {
        const int d = dst[i];
        const int p = atomicAdd(&cursor[d], 1);
        order[base[d] + p] = i;
    }
}

// ---------------------------------------------------------------------------
// K2a: edge MLP as MFMA GEMM, CSR-position-ordered output (bf16).
//   processes CSR positions [lo + 64*blk, +64) for node range [n0,n1)
//   h = silu(esc[e]@Wfc1/sqrt10)  (f32 VALU)  -> bf16 LDS (XOR-swizzled)
//   w = h @ Wfc2 / sqrt64         (mfma_f32_16x16x32_bf16, K=64)
//   wbuf[(pos-lo)*192 + c] = bf16(w)
// ---------------------------------------------------------------------------
__global__ __launch_bounds__(256) void k_edge_mlp(
    const float* __restrict__ esc, const int* __restrict__ order,
    const int* __restrict__ base,
    const float* __restrict__ Wfc1, const float* __restrict__ Wfc2,
    unsigned short* __restrict__ wbuf, int n0, int n1, int N, int E)
{
    __shared__ float esc_l[640];
    __shared__ float w1_l[640];
    __shared__ __align__(16) char hb[64 * 64 * 2];     // [row][k] bf16, swz ^((r&7)<<4)
    __shared__ __align__(16) char w2t[192 * 64 * 2];   // [col][k] bf16, swz ^((c&7)<<4)
    const int tid = threadIdx.x;
    const int lo = (n0 == 0) ? 0 : base[n0];
    const int hi = (n1 >= N) ? E : base[n1];
    const int p0 = lo + blockIdx.x * 64;
    if (p0 >= hi) return;

    for (int i = tid; i < 640; i += 256) w1_l[i] = Wfc1[i];
    for (int i = tid; i < 64 * 192; i += 256) {
        int k = i / 192, c = i - k * 192;
        int byte = (((c << 6) + k) << 1) ^ ((c & 7) << 4);
        *(unsigned short*)(w2t + byte) = f2bf(Wfc2[i]);
    }
    for (int i = tid; i < 640; i += 256) {
        int r = i / 10, q = i - r * 10;
        int pos = p0 + r;
        int e = order[pos < hi ? pos : hi - 1];
        esc_l[i] = esc[(size_t)e * 10 + q];
    }
    __syncthreads();
    // ---- h (f32): thread -> edge r=tid>>2, cols c0=(tid&3)*16
    {
        const int r = tid >> 2, c0 = (tid & 3) << 4;
        float hval[16];
        #pragma unroll
        for (int c = 0; c < 16; c++) {
            float acc = 0.f;
            #pragma unroll
            for (int q = 0; q < 10; q++) acc += esc_l[r * 10 + q] * w1_l[q * 64 + c0 + c];
            acc *= INV_SQRT10;
            hval[c] = acc / (1.f + __expf(-acc));
        }
        unsigned pk[8];
        #pragma unroll
        for (int j = 0; j < 8; j++)
            pk[j] = (unsigned)f2bf(hval[2 * j]) | ((unsigned)f2bf(hval[2 * j + 1]) << 16);
        const int swz = (r & 7) << 4;
        const int b0 = (r << 7) + (c0 << 1);
        *(uint4*)(hb + (b0 ^ swz)) = make_uint4(pk[0], pk[1], pk[2], pk[3]);
        *(uint4*)(hb + ((b0 + 16) ^ swz)) = make_uint4(pk[4], pk[5], pk[6], pk[7]);
    }
    __syncthreads();
    // ---- MFMA: wave wv -> rows [wv*16, wv*16+16), 12 col-tiles, K=64
    const int wv = tid >> 6, lane = tid & 63;
    const int mrow = lane & 15, kgrp = lane >> 4;
    f32x4 acc[12];
    #pragma unroll
    for (int t = 0; t < 12; t++) acc[t] = (f32x4){0.f, 0.f, 0.f, 0.f};
    #pragma unroll
    for (int kc = 0; kc < 2; kc++) {
        const int r = wv * 16 + mrow;
        const int abyte = ((r << 7) + (kc << 6) + (kgrp << 4)) ^ ((r & 7) << 4);
        const bf16x8 afrag = *(const bf16x8*)(hb + abyte);
        #pragma unroll
        for (int t = 0; t < 12; t++) {
            const int c = t * 16 + mrow;
            const int bbyte = ((c << 7) + (kc << 6) + (kgrp << 4)) ^ ((c & 7) << 4);
            const bf16x8 bfrag = *(const bf16x8*)(w2t + bbyte);
            acc[t] = __builtin_amdgcn_mfma_f32_16x16x32_bf16(afrag, bfrag, acc[t], 0, 0, 0);
        }
    }
    // ---- store (fold 1/sqrt64), bf16, CSR-positional
    #pragma unroll
    for (int t = 0; t < 12; t++) {
        #pragma unroll
        for (int rg = 0; rg < 4; rg++) {
            const int rloc = wv * 16 + kgrp * 4 + rg;
            const int pos = p0 + rloc;
            if (pos < hi)
                wbuf[(size_t)(pos - lo) * 192 + t * 16 + mrow] = f2bf(acc[t][rg] * INV_SQRT64);
        }
    }
}

// ---------------------------------------------------------------------------
// K2b: aggregation + node finalize, fused. wave-per-dst-node over CSR.
//   reads precomputed w (bf16, CSR order), accumulates messages in registers,
//   then does deg-normalize, alpha, lin2, skip, gating/output in-wave.
// ---------------------------------------------------------------------------
template <int OS, bool FINAL>
__global__ __launch_bounds__(256) void k_agg_out(
    const float* __restrict__ hs, const float* __restrict__ hv,
    const int* __restrict__ src, const float* __restrict__ sh,
    const int* __restrict__ order, const int* __restrict__ base,
    const int* __restrict__ cnt, const unsigned short* __restrict__ wbuf,
    const float* __restrict__ attr,
    const float* __restrict__ scs, const float* __restrict__ scv,
    const float* __restrict__ W2s, const float* __restrict__ W2v,
    const float* __restrict__ Wa,
    float* __restrict__ outS, float* __restrict__ outV,
    int n0, int n1, int N, int E)
{
    __shared__ float ms_l[4][96];
    __shared__ float mv_l[4][288];
    __shared__ float gate_l[4][32];
    const int wave = threadIdx.x >> 6, lane = threadIdx.x & 63;
    const int n = n0 + blockIdx.x * 4 + wave;
    const bool valid = n < n1;
    const int lo = (n0 == 0) ? 0 : base[n0];
    const int colB = (lane < 32) ? (128 + lane) : (160 + lane - 32);

    float aS = 0.f, aSB = 0.f;
    float aV0 = 0.f, aV1 = 0.f, aV2 = 0.f;
    float aB0 = 0.f, aB1 = 0.f, aB2 = 0.f;
    int c_ = 0;
    if (valid) {
        const int b0 = base[n];
        c_ = cnt[n];
        const unsigned short* wp = wbuf + (size_t)(b0 - lo) * 192;
        for (int j = 0; j < c_; ++j, wp += 192) {
            const int e = order[b0 + j];
            const int s = src[e];
            const float w1 = bf2f(wp[lane]);
            const float w2 = bf2f(wp[64 + lane]);
            const float wB = bf2f(wp[colB]);
            const float gs = hs[(size_t)s * 64 + lane];
            float gv0 = 0.f, gv1 = 0.f, gv2 = 0.f;
            if (lane < 32) {
                gv0 = hv[(size_t)s * 96 + lane * 3 + 0];
                gv1 = hv[(size_t)s * 96 + lane * 3 + 1];
                gv2 = hv[(size_t)s * 96 + lane * 3 + 2];
            }
            const float4 s4 = ((const float4*)sh)[e];
            const float gvdot = gv0 * s4.y + gv1 * s4.z + gv2 * s4.w;
            const float gvd = __shfl(gvdot, lane & 31);
            aS  += gs * s4.x * w1;
            aSB += gvd * INV_SQRT3 * wB;
            aV0 += gs * s4.y * w2;
            aV1 += gs * s4.z * w2;
            aV2 += gs * s4.w * w2;
            aB0 += gv0 * s4.x * wB;
            aB1 += gv1 * s4.x * wB;
            aB2 += gv2 * s4.x * wB;
        }
    }
    const float invd = 1.f / (float)max(c_, 1);
    if (valid) {
        ms_l[wave][lane] = aS * invd;
        if (lane >= 32) ms_l[wave][64 + (lane - 32)] = aSB * invd;
        mv_l[wave][lane * 3 + 0] = aV0 * invd;
        mv_l[wave][lane * 3 + 1] = aV1 * invd;
        mv_l[wave][lane * 3 + 2] = aV2 * invd;
        if (lane < 32) {
            mv_l[wave][(64 + lane) * 3 + 0] = aB0 * invd;
            mv_l[wave][(64 + lane) * 3 + 1] = aB1 * invd;
            mv_l[wave][(64 + lane) * 3 + 2] = aB2 * invd;
        }
    }
    __syncthreads();
    float sA = 0.f, sB = 0.f, vA = 0.f, vB = 0.f;
    if (valid) {
        const float a = attr[n];
        float p = ms_l[wave][lane] * Wa[lane];
        if (lane < 32) p += ms_l[wave][64 + lane] * Wa[64 + lane];
        #pragma unroll
        for (int o = 32; o > 0; o >>= 1) p += __shfl_xor(p, o);
        const float alpha = p * INV_SQRT96 * a;
        const int laneB = lane & 31;
        float acc0 = 0.f, acc1 = 0.f;
        #pragma unroll 8
        for (int j = 0; j < 96; j++) {
            float m = ms_l[wave][j];
            acc0 += m * W2s[j * OS + lane];
            if (OS == 96) acc1 += m * W2s[j * 96 + 64 + laneB];
        }
        sA = scs[(size_t)n * OS + lane] + alpha * (acc0 * INV_SQRT96 * a);
        if (OS == 96) sB = scs[(size_t)n * 96 + 64 + laneB] + alpha * (acc1 * INV_SQRT96 * a);
        const int k1 = lane / 3, i1 = lane - k1 * 3;
        const int p2 = (lane < 32) ? (64 + lane) : 95;
        const int k2 = p2 / 3, i2 = p2 - k2 * 3;
        float av0 = 0.f, av1 = 0.f;
        #pragma unroll 8
        for (int j = 0; j < 96; j++) {
            av0 += mv_l[wave][j * 3 + i1] * W2v[j * 32 + k1];
            av1 += mv_l[wave][j * 3 + i2] * W2v[j * 32 + k2];
        }
        vA = scv[(size_t)n * 96 + lane] + alpha * (av0 * INV_SQRT96 * a);
        vB = scv[(size_t)n * 96 + p2] + alpha * (av1 * INV_SQRT96 * a);
    }
    if (!FINAL) {
        if (valid && lane < 32) gate_l[wave][lane] = 1.f / (1.f + __expf(-sB));
    }
    __syncthreads();
    if (valid) {
        if (FINAL) {
            float* o = outS + (size_t)n * 160;
            o[lane] = sA;
            o[64 + lane] = vA;
            if (lane < 32) o[128 + lane] = vB;
        } else {
            outS[(size_t)n * 64 + lane] = sA / (1.f + __expf(-sA));
            const int k1 = lane / 3;
            outV[(size_t)n * 96 + lane] = vA * gate_l[wave][k1];
            if (lane < 32) {
                const int k2 = (64 + lane) / 3;
                outV[(size_t)n * 96 + 64 + lane] = vB * gate_l[wave][k2];
            }
        }
    }
}

// ---------------------------------------------------------------------------
extern "C" void kernel_launch(void* const* d_in, const int* in_sizes, int n_in,
                              void* d_out, int out_size, void* d_ws, size_t ws_size,
                              hipStream_t stream)
{
    const float* node_s = (const float*)d_in[0];
    const float* node_v = (const float*)d_in[1];
    const float* attr   = (const float*)d_in[2];
    const int*   esrc   = (const int*)d_in[3];
    const int*   edst   = (const int*)d_in[4];
    const float* esh    = (const float*)d_in[5];
    const float* esc    = (const float*)d_in[6];
    const float* W[18];
    for (int i = 0; i < 18; i++) W[i] = (const float*)d_in[7 + i];
    // per layer: 0 sc_s, 1 sc_v, 2 lin1_s, 3 lin1_v, 4 fc1, 5 fc2, 6 lin2_s, 7 lin2_v, 8 alpha

    const int N = in_sizes[0] / 64;
    const int E = in_sizes[3];

    float* ws  = (float*)d_ws;
    float* hs  = ws;                          // N*64
    float* hvb = hs  + (size_t)N * 64;        // N*96
    float* scs = hvb + (size_t)N * 96;        // N*96
    float* scv = scs + (size_t)N * 96;        // N*96
    float* gsb = scv + (size_t)N * 96;        // N*64
    float* vgb = gsb + (size_t)N * 64;        // N*96
    int*   cnt    = (int*)(vgb + (size_t)N * 96);  // N
    int*   cursor = cnt + N;                        // N  (adjacent: one memset)
    int*   basei  = cursor + N;                     // N
    int*   order  = basei + N;                      // E
    unsigned short* wbuf = (unsigned short*)(order + E);  // capQ*192

    const int nb  = (N + 3) / 4;
    const int ebk = (E + 255) / 256;
    const int emb = (E + 63) / 64;   // k_edge_mlp grid (covers worst-case skew)
    const int NQ  = 4;
    const int Q   = (N + NQ - 1) / NQ;
    const int qb  = (Q + 3) / 4;

    // ---- CSR build (graph identical for both layers)
    hipMemsetAsync(cnt, 0, (size_t)2 * N * sizeof(int), stream);  // cnt + cursor
    k_count<<<ebk, 256, 0, stream>>>(edst, cnt, E);
    k_scan<<<1, 1024, 0, stream>>>(cnt, basei, N);
    k_scatter<<<ebk, 256, 0, stream>>>(edst, basei, cursor, order, E);

    // ---- layer 1
    k_node_lin<96><<<nb, 256, 0, stream>>>(node_s, node_v, attr, W[2], W[3], W[0], W[1],
                                           hs, hvb, scs, scv, N);
    for (int q = 0; q < NQ; q++) {
        const int n0 = q * Q, n1 = min(N, (q + 1) * Q);
        if (n0 >= n1) break;
        k_edge_mlp<<<emb, 256, 0, stream>>>(esc, order, basei, W[4], W[5], wbuf,
                                            n0, n1, N, E);
        k_agg_out<96, false><<<qb, 256, 0, stream>>>(hs, hvb, esrc, esh, order, basei,
                                                     cnt, wbuf, attr, scs, scv,
                                                     W[6], W[7], W[8], gsb, vgb,
                                                     n0, n1, N, E);
    }
    // ---- layer 2
    k_node_lin<64><<<nb, 256, 0, stream>>>(gsb, vgb, attr, W[11], W[12], W[9], W[10],
                                           hs, hvb, scs, scv, N);
    for (int q = 0; q < NQ; q++) {
        const int n0 = q * Q, n1 = min(N, (q + 1) * Q);
        if (n0 >= n1) break;
        k_edge_mlp<<<emb, 256, 0, stream>>>(esc, order, basei, W[13], W[14], wbuf,
                                            n0, n1, N, E);
        k_agg_out<64, true><<<qb, 256, 0, stream>>>(hs, hvb, esrc, esh, order, basei,
                                                    cnt, wbuf, attr, scs, scv,
                                                    W[15], W[16], W[17],
                                                    (float*)d_out, nullptr,
                                                    n0, n1, N, E);
    }
}

// Round 4
// 906.846 us; speedup vs baseline: 3.5379x; 1.2843x over previous
//
#include <hip/hip_runtime.h>
#include <hip/hip_bf16.h>

#define INV_SQRT10 0.31622776601683794f
#define INV_SQRT64 0.125f
#define INV_SQRT32 0.17677669529663687f
#define INV_SQRT96 0.10206207261596575f
#define INV_SQRT3  0.5773502691896258f

typedef __attribute__((ext_vector_type(4))) float f32x4;
typedef __attribute__((ext_vector_type(8))) short bf16x8;

__device__ __forceinline__ unsigned short f2bf(float x) {
    union { float f; unsigned u; } v; v.f = x;
    unsigned r = v.u + 0x7FFF + ((v.u >> 16) & 1);
    return (unsigned short)(r >> 16);
}
__device__ __forceinline__ float bf2f(unsigned short u) {
    union { unsigned u; float f; } v; v.u = ((unsigned)u) << 16;
    return v.f;
}

// ---------------------------------------------------------------------------
// K1: node linears as MFMA GEMMs. 128 nodes / block, 4 waves.
//   GEMM1: xs(128,64) @ [Wl1s|Wscs](64,64+OS)      -> hs, scs
//   GEMM2: xv-planes(384,32) @ [Wl1v|Wscv](32,64)  -> hv, scv (plane-major)
//   UI_IN: input xv layout true=(n,u*3+i) [node_v], false=(n,i*32+u) [vgb]
//   outputs: hs(N,64); hv,scv plane-major (N, i*32+u); scs(N,OS)
// ---------------------------------------------------------------------------
template <int OS, bool UI_IN>
__global__ __launch_bounds__(256) void k_node_mfma(
    const float* __restrict__ xs, const float* __restrict__ xv,
    const float* __restrict__ attr,
    const float* __restrict__ Wl1s, const float* __restrict__ Wl1v,
    const float* __restrict__ Wscs, const float* __restrict__ Wscv,
    float* __restrict__ hs, float* __restrict__ hv,
    float* __restrict__ scs, float* __restrict__ scv, int N)
{
    constexpr int NC1 = 64 + OS;          // GEMM1 output cols
    constexpr int CT1 = NC1 / 16;         // col tiles
    __shared__ __align__(16) char As[128 * 128];       // [r][k=64] bf16 ^((r&7)<<4)
    __shared__ __align__(16) char Av[384 * 64];        // [rv][u=32] bf16 ^((rv&3)<<4)
    __shared__ __align__(16) char Bs[NC1 * 128];       // [c][k=64] bf16 ^((c&7)<<4)
    __shared__ __align__(16) char Bv[64 * 64];         // [c][u=32] bf16 ^((c&3)<<4)
    __shared__ float attr_l[128];
    const int tid = threadIdx.x;
    const int n0 = blockIdx.x * 128;

    // ---- stage A (xs)
    for (int i = tid; i < 128 * 64; i += 256) {
        const int r = i >> 6, k = i & 63;
        const float x = (n0 + r < N) ? xs[(size_t)(n0 + r) * 64 + k] : 0.f;
        *(unsigned short*)(As + (((r << 7) + (k << 1)) ^ ((r & 7) << 4))) = f2bf(x);
    }
    // ---- stage A vector planes
    for (int i = tid; i < 128 * 96; i += 256) {
        const int r = i / 96, rem = i - r * 96;
        int u, ic;
        if (UI_IN) { u = rem / 3; ic = rem - u * 3; }
        else       { ic = rem >> 5; u = rem & 31; }
        const float x = (n0 + r < N) ? xv[(size_t)(n0 + r) * 96 + rem] : 0.f;
        const int rv = ic * 128 + r;
        *(unsigned short*)(Av + (((rv << 6) + (u << 1)) ^ ((rv & 3) << 4))) = f2bf(x);
    }
    // ---- stage B scalar: Wl1s cols 0..63, Wscs cols 64..64+OS
    for (int i = tid; i < 64 * 64; i += 256) {
        const int k = i >> 6, c = i & 63;
        *(unsigned short*)(Bs + (((c << 7) + (k << 1)) ^ ((c & 7) << 4))) = f2bf(Wl1s[i]);
    }
    for (int i = tid; i < 64 * OS; i += 256) {
        const int k = i / OS, c = 64 + (i - k * OS);
        *(unsigned short*)(Bs + (((c << 7) + (k << 1)) ^ ((c & 7) << 4))) = f2bf(Wscs[i]);
    }
    // ---- stage B vector: Wl1v cols 0..31, Wscv cols 32..63
    for (int i = tid; i < 32 * 32; i += 256) {
        const int u = i >> 5, c = i & 31;
        *(unsigned short*)(Bv + (((c << 6) + (u << 1)) ^ ((c & 3) << 4))) = f2bf(Wl1v[i]);
    }
    for (int i = tid; i < 32 * 32; i += 256) {
        const int u = i >> 5, c = 32 + (i & 31);
        *(unsigned short*)(Bv + (((c << 6) + (u << 1)) ^ ((c & 3) << 4))) = f2bf(Wscv[i]);
    }
    if (tid < 128) attr_l[tid] = (n0 + tid < N) ? attr[n0 + tid] : 0.f;
    __syncthreads();

    const int wv = tid >> 6, lane = tid & 63;
    const int mrow = lane & 15, kg = lane >> 4;

    // ---- GEMM1: wave wv handles rows [wv*32, wv*32+32)
    #pragma unroll
    for (int rt = 0; rt < 2; rt++) {
        const int rbase = wv * 32 + rt * 16;
        const int r = rbase + mrow;
        f32x4 acc[CT1];
        #pragma unroll
        for (int t = 0; t < CT1; t++) acc[t] = (f32x4){0.f, 0.f, 0.f, 0.f};
        #pragma unroll
        for (int kc = 0; kc < 2; kc++) {
            const bf16x8 a = *(const bf16x8*)(As + (((r << 7) + (kc << 6) + (kg << 4)) ^ ((r & 7) << 4)));
            #pragma unroll
            for (int t = 0; t < CT1; t++) {
                const int c = t * 16 + mrow;
                const bf16x8 b = *(const bf16x8*)(Bs + (((c << 7) + (kc << 6) + (kg << 4)) ^ ((c & 7) << 4)));
                acc[t] = __builtin_amdgcn_mfma_f32_16x16x32_bf16(a, b, acc[t], 0, 0, 0);
            }
        }
        #pragma unroll
        for (int t = 0; t < CT1; t++) {
            const int col = t * 16 + mrow;
            #pragma unroll
            for (int rg = 0; rg < 4; rg++) {
                const int row = rbase + kg * 4 + rg;
                const int n = n0 + row;
                if (n < N) {
                    const float val = acc[t][rg] * INV_SQRT64 * attr_l[row];
                    if (col < 64) hs[(size_t)n * 64 + col] = val;
                    else          scs[(size_t)n * OS + (col - 64)] = val;
                }
            }
        }
    }
    // ---- GEMM2: 24 row-tiles (rv = ic*128 + nloc), wave handles 6
    #pragma unroll
    for (int j = 0; j < 6; j++) {
        const int rbase = (wv * 6 + j) * 16;
        const int rv = rbase + mrow;
        const bf16x8 a = *(const bf16x8*)(Av + (((rv << 6) + (kg << 4)) ^ ((rv & 3) << 4)));
        f32x4 acc2[4];
        #pragma unroll
        for (int t = 0; t < 4; t++) acc2[t] = (f32x4){0.f, 0.f, 0.f, 0.f};
        #pragma unroll
        for (int t = 0; t < 4; t++) {
            const int c = t * 16 + mrow;
            const bf16x8 b = *(const bf16x8*)(Bv + (((c << 6) + (kg << 4)) ^ ((c & 3) << 4)));
            acc2[t] = __builtin_amdgcn_mfma_f32_16x16x32_bf16(a, b, acc2[t], 0, 0, 0);
        }
        #pragma unroll
        for (int t = 0; t < 4; t++) {
            const int col = t * 16 + mrow;
            #pragma unroll
            for (int rg = 0; rg < 4; rg++) {
                const int rv2 = rbase + kg * 4 + rg;
                const int ic = rv2 >> 7, nloc = rv2 & 127;
                const int n = n0 + nloc;
                if (n < N) {
                    const float val = acc2[t][rg] * INV_SQRT32 * attr_l[nloc];
                    if (col < 32) hv[(size_t)n * 96 + ic * 32 + col] = val;
                    else          scv[(size_t)n * 96 + ic * 32 + (col - 32)] = val;
                }
            }
        }
    }
}

// ---------------------------------------------------------------------------
// CSR build: count -> scan -> scatter. Same graph both layers; built once.
// ---------------------------------------------------------------------------
__global__ __launch_bounds__(256) void k_count(const int* __restrict__ dst,
                                               int* __restrict__ cnt, int E)
{
    int i = blockIdx.x * 256 + threadIdx.x;
    if (i < E) atomicAdd(&cnt[dst[i]], 1);
}

__global__ __launch_bounds__(1024) void k_scan(const int* __restrict__ cnt,
                                               int* __restrict__ base, int N)
{
    __shared__ int lds[1024];
    const int t = threadIdx.x;
    const int chunk = (N + 1023) / 1024;
    const int s = t * chunk, e = min(s + chunk, N);
    int local = 0;
    for (int i = s; i < e; i++) local += cnt[i];
    lds[t] = local;
    __syncthreads();
    for (int off = 1; off < 1024; off <<= 1) {
        int v = (t >= off) ? lds[t - off] : 0;
        __syncthreads();
        lds[t] += v;
        __syncthreads();
    }
    int running = lds[t] - local;  // exclusive prefix
    for (int i = s; i < e; i++) { base[i] = running; running += cnt[i]; }
}

__global__ __launch_bounds__(256) void k_scatter(const int* __restrict__ dst,
                                                 const int* __restrict__ base,
                                                 int* __restrict__ cursor,
                                                 int* __restrict__ order, int E)
{
    int i = blockIdx.x * 256 + threadIdx.x;
    if (i < E) {
        const int d = dst[i];
        const int p = atomicAdd(&cursor[d], 1);
        order[base[d] + p] = i;
    }
}

// ---------------------------------------------------------------------------
// K2a: edge MLP as MFMA GEMM, CSR-position-ordered packed output.
//   wbuf[pos][lane] = ushort4{ w[lane], w[64+lane], w[128+lane], 0 } (bf16)
// ---------------------------------------------------------------------------
__global__ __launch_bounds__(256) void k_edge_mlp(
    const float* __restrict__ esc, const int* __restrict__ order,
    const int* __restrict__ base,
    const float* __restrict__ Wfc1, const float* __restrict__ Wfc2,
    unsigned short* __restrict__ wbuf, int n0, int n1, int N, int E)
{
    __shared__ float esc_l[640];
    __shared__ float w1_l[640];
    __shared__ __align__(16) char hb[64 * 64 * 2];     // [row][k] bf16, swz ^((r&7)<<4)
    __shared__ __align__(16) char w2t[192 * 64 * 2];   // [col][k] bf16, swz ^((c&7)<<4)
    const int tid = threadIdx.x;
    const int lo = (n0 == 0) ? 0 : base[n0];
    const int hi = (n1 >= N) ? E : base[n1];
    const int p0 = lo + blockIdx.x * 64;
    if (p0 >= hi) return;

    for (int i = tid; i < 640; i += 256) w1_l[i] = Wfc1[i];
    for (int i = tid; i < 64 * 192; i += 256) {
        int k = i / 192, c = i - k * 192;
        int byte = (((c << 6) + k) << 1) ^ ((c & 7) << 4);
        *(unsigned short*)(w2t + byte) = f2bf(Wfc2[i]);
    }
    for (int i = tid; i < 640; i += 256) {
        int r = i / 10, q = i - r * 10;
        int pos = p0 + r;
        int e = order[pos < hi ? pos : hi - 1];
        esc_l[i] = esc[(size_t)e * 10 + q];
    }
    __syncthreads();
    // ---- h (f32): thread -> edge r=tid>>2, cols c0=(tid&3)*16
    {
        const int r = tid >> 2, c0 = (tid & 3) << 4;
        float hval[16];
        #pragma unroll
        for (int c = 0; c < 16; c++) {
            float acc = 0.f;
            #pragma unroll
            for (int q = 0; q < 10; q++) acc += esc_l[r * 10 + q] * w1_l[q * 64 + c0 + c];
            acc *= INV_SQRT10;
            hval[c] = acc / (1.f + __expf(-acc));
        }
        unsigned pk[8];
        #pragma unroll
        for (int j = 0; j < 8; j++)
            pk[j] = (unsigned)f2bf(hval[2 * j]) | ((unsigned)f2bf(hval[2 * j + 1]) << 16);
        const int swz = (r & 7) << 4;
        const int b0 = (r << 7) + (c0 << 1);
        *(uint4*)(hb + (b0 ^ swz)) = make_uint4(pk[0], pk[1], pk[2], pk[3]);
        *(uint4*)(hb + ((b0 + 16) ^ swz)) = make_uint4(pk[4], pk[5], pk[6], pk[7]);
    }
    __syncthreads();
    // ---- MFMA: wave wv -> rows [wv*16, wv*16+16), 12 col-tiles, K=64
    const int wv = tid >> 6, lane = tid & 63;
    const int mrow = lane & 15, kgrp = lane >> 4;
    f32x4 acc[12];
    #pragma unroll
    for (int t = 0; t < 12; t++) acc[t] = (f32x4){0.f, 0.f, 0.f, 0.f};
    #pragma unroll
    for (int kc = 0; kc < 2; kc++) {
        const int r = wv * 16 + mrow;
        const int abyte = ((r << 7) + (kc << 6) + (kgrp << 4)) ^ ((r & 7) << 4);
        const bf16x8 afrag = *(const bf16x8*)(hb + abyte);
        #pragma unroll
        for (int t = 0; t < 12; t++) {
            const int c = t * 16 + mrow;
            const int bbyte = ((c << 7) + (kc << 6) + (kgrp << 4)) ^ ((c & 7) << 4);
            const bf16x8 bfrag = *(const bf16x8*)(w2t + bbyte);
            acc[t] = __builtin_amdgcn_mfma_f32_16x16x32_bf16(afrag, bfrag, acc[t], 0, 0, 0);
        }
    }
    // ---- packed store: slot (tb*16+mrow) gets cols {c, c+64, c+128}
    #pragma unroll
    for (int rg = 0; rg < 4; rg++) {
        const int rloc = wv * 16 + kgrp * 4 + rg;
        const int pos = p0 + rloc;
        if (pos < hi) {
            #pragma unroll
            for (int tb = 0; tb < 4; tb++) {
                ushort4 pk;
                pk.x = f2bf(acc[tb][rg] * INV_SQRT64);
                pk.y = f2bf(acc[tb + 4][rg] * INV_SQRT64);
                pk.z = f2bf(acc[tb + 8][rg] * INV_SQRT64);
                pk.w = 0;
                *(ushort4*)(wbuf + (size_t)(pos - lo) * 256 + (size_t)(tb * 16 + mrow) * 4) = pk;
            }
        }
    }
}

// ---------------------------------------------------------------------------
// K2b: aggregation + node finalize, fused. wave-per-dst-node over CSR.
//   hv/scv plane-major (n, i*32+u); vgb output plane-major.
// ---------------------------------------------------------------------------
template <int OS, bool FINAL>
__global__ __launch_bounds__(256) void k_agg_out(
    const float* __restrict__ hs, const float* __restrict__ hv,
    const int* __restrict__ src, const float* __restrict__ sh,
    const int* __restrict__ order, const int* __restrict__ base,
    const int* __restrict__ cnt, const unsigned short* __restrict__ wbuf,
    const float* __restrict__ attr,
    const float* __restrict__ scs, const float* __restrict__ scv,
    const float* __restrict__ W2s, const float* __restrict__ W2v,
    const float* __restrict__ Wa,
    float* __restrict__ outS, float* __restrict__ outV,
    int n0, int n1, int N, int E)
{
    __shared__ float ms_l[4][96];
    __shared__ float mv_l[4][288];     // plane-major: [i*96 + u]
    __shared__ float gate_l[4][32];
    const int wave = threadIdx.x >> 6, lane = threadIdx.x & 63;
    const int n = n0 + blockIdx.x * 4 + wave;
    const bool valid = n < n1;
    const int lo = (n0 == 0) ? 0 : base[n0];
    const ushort4* __restrict__ wbuf4 = (const ushort4*)wbuf;

    float aS = 0.f, aSB = 0.f;
    float aV0 = 0.f, aV1 = 0.f, aV2 = 0.f;
    float aB0 = 0.f, aB1 = 0.f, aB2 = 0.f;
    int c_ = 0;
    if (valid) {
        const int b0 = base[n];
        c_ = cnt[n];
        for (int j = 0; j < c_; ++j) {
            const int e = order[b0 + j];
            const int s = src[e];
            const ushort4 wq = wbuf4[(size_t)(b0 - lo + j) * 64 + lane];
            const float w1 = bf2f(wq.x);
            const float w2 = bf2f(wq.y);
            const float wB = bf2f(wq.z);
            const float gs = hs[(size_t)s * 64 + lane];
            float gv0 = 0.f, gv1 = 0.f, gv2 = 0.f;
            if (lane < 32) {
                gv0 = hv[(size_t)s * 96 + lane];
                gv1 = hv[(size_t)s * 96 + 32 + lane];
                gv2 = hv[(size_t)s * 96 + 64 + lane];
            }
            const float4 s4 = ((const float4*)sh)[e];
            const float gvdot = gv0 * s4.y + gv1 * s4.z + gv2 * s4.w;
            const float gvd = __shfl(gvdot, lane & 31);
            aS  += gs * s4.x * w1;
            aSB += gvd * INV_SQRT3 * wB;
            aV0 += gs * s4.y * w2;
            aV1 += gs * s4.z * w2;
            aV2 += gs * s4.w * w2;
            aB0 += gv0 * s4.x * wB;
            aB1 += gv1 * s4.x * wB;
            aB2 += gv2 * s4.x * wB;
        }
    }
    const float invd = 1.f / (float)max(c_, 1);
    if (valid) {
        ms_l[wave][lane] = aS * invd;
        if (lane >= 32) ms_l[wave][64 + (lane - 32)] = aSB * invd;
        // m_v rows 0..63 are (gs*shv*w2): row u=lane, component i
        mv_l[wave][0 * 96 + lane] = aV0 * invd;
        mv_l[wave][1 * 96 + lane] = aV1 * invd;
        mv_l[wave][2 * 96 + lane] = aV2 * invd;
        if (lane < 32) {   // rows 64..95: gv_i * sh0 * w3
            mv_l[wave][0 * 96 + 64 + lane] = aB0 * invd;
            mv_l[wave][1 * 96 + 64 + lane] = aB1 * invd;
            mv_l[wave][2 * 96 + 64 + lane] = aB2 * invd;
        }
    }
    __syncthreads();
    float sA = 0.f, sB = 0.f, vA = 0.f, vB = 0.f;
    if (valid) {
        const float a = attr[n];
        float p = ms_l[wave][lane] * Wa[lane];
        if (lane < 32) p += ms_l[wave][64 + lane] * Wa[64 + lane];
        #pragma unroll
        for (int o = 32; o > 0; o >>= 1) p += __shfl_xor(p, o);
        const float alpha = p * INV_SQRT96 * a;
        const int laneB = lane & 31;
        float acc0 = 0.f, acc1 = 0.f;
        #pragma unroll 8
        for (int j = 0; j < 96; j++) {
            float m = ms_l[wave][j];
            acc0 += m * W2s[j * OS + lane];
            if (OS == 96) acc1 += m * W2s[j * 96 + 64 + laneB];
        }
        sA = scs[(size_t)n * OS + lane] + alpha * (acc0 * INV_SQRT96 * a);
        if (OS == 96) sB = scs[(size_t)n * 96 + 64 + laneB] + alpha * (acc1 * INV_SQRT96 * a);
        // vector: lane -> (i1 = lane>>5, k1 = lane&31); second slot (i=2, k=lane) lane<32
        const int i1 = lane >> 5, k1 = lane & 31;
        float av0 = 0.f, av1 = 0.f;
        #pragma unroll 8
        for (int j = 0; j < 96; j++) {
            av0 += mv_l[wave][i1 * 96 + j] * W2v[j * 32 + k1];
            av1 += mv_l[wave][2 * 96 + j] * W2v[j * 32 + laneB];
        }
        vA = scv[(size_t)n * 96 + lane] + alpha * (av0 * INV_SQRT96 * a);
        if (lane < 32)
            vB = scv[(size_t)n * 96 + 64 + lane] + alpha * (av1 * INV_SQRT96 * a);
    }
    if (!FINAL) {
        if (valid && lane < 32) gate_l[wave][lane] = 1.f / (1.f + __expf(-sB));
    }
    __syncthreads();
    if (valid) {
        const int i1 = lane >> 5, k1 = lane & 31;
        if (FINAL) {
            float* o = outS + (size_t)n * 160;
            o[lane] = sA;
            o[64 + k1 * 3 + i1] = vA;                // v2 slot (k1, i1)
            if (lane < 32) o[64 + lane * 3 + 2] = vB;
        } else {
            outS[(size_t)n * 64 + lane] = sA / (1.f + __expf(-sA));
            outV[(size_t)n * 96 + lane] = vA * gate_l[wave][k1];
            if (lane < 32)
                outV[(size_t)n * 96 + 64 + lane] = vB * gate_l[wave][lane];
        }
    }
}

// ---------------------------------------------------------------------------
extern "C" void kernel_launch(void* const* d_in, const int* in_sizes, int n_in,
                              void* d_out, int out_size, void* d_ws, size_t ws_size,
                              hipStream_t stream)
{
    const float* node_s = (const float*)d_in[0];
    const float* node_v = (const float*)d_in[1];
    const float* attr   = (const float*)d_in[2];
    const int*   esrc   = (const int*)d_in[3];
    const int*   edst   = (const int*)d_in[4];
    const float* esh    = (const float*)d_in[5];
    const float* esc    = (const float*)d_in[6];
    const float* W[18];
    for (int i = 0; i < 18; i++) W[i] = (const float*)d_in[7 + i];
    // per layer: 0 sc_s, 1 sc_v, 2 lin1_s, 3 lin1_v, 4 fc1, 5 fc2, 6 lin2_s, 7 lin2_v, 8 alpha

    const int N = in_sizes[0] / 64;
    const int E = in_sizes[3];

    float* ws  = (float*)d_ws;
    float* hs  = ws;                          // N*64
    float* hvb = hs  + (size_t)N * 64;        // N*96 (plane-major)
    float* scs = hvb + (size_t)N * 96;        // N*96
    float* scv = scs + (size_t)N * 96;        // N*96 (plane-major)
    float* gsb = scv + (size_t)N * 96;        // N*64
    float* vgb = gsb + (size_t)N * 64;        // N*96 (plane-major)
    int*   cnt    = (int*)(vgb + (size_t)N * 96);  // N
    int*   cursor = cnt + N;                        // N  (adjacent: one memset)
    int*   basei  = cursor + N;                     // N
    int*   order  = basei + N;                      // E
    unsigned short* wbuf = (unsigned short*)(order + E);  // capQ*256 u16

    const int nb2 = (N + 127) / 128;
    const int ebk = (E + 255) / 256;
    const int emb = (E + 63) / 64;   // k_edge_mlp grid (early-exit past quarter)
    const int NQ  = 4;
    const int Q   = (N + NQ - 1) / NQ;
    const int qb  = (Q + 3) / 4;

    // ---- CSR build (graph identical for both layers)
    hipMemsetAsync(cnt, 0, (size_t)2 * N * sizeof(int), stream);  // cnt + cursor
    k_count<<<ebk, 256, 0, stream>>>(edst, cnt, E);
    k_scan<<<1, 1024, 0, stream>>>(cnt, basei, N);
    k_scatter<<<ebk, 256, 0, stream>>>(edst, basei, cursor, order, E);

    // ---- layer 1
    k_node_mfma<96, true><<<nb2, 256, 0, stream>>>(node_s, node_v, attr,
                                                   W[2], W[3], W[0], W[1],
                                                   hs, hvb, scs, scv, N);
    for (int q = 0; q < NQ; q++) {
        const int n0 = q * Q, n1 = min(N, (q + 1) * Q);
        if (n0 >= n1) break;
        k_edge_mlp<<<emb, 256, 0, stream>>>(esc, order, basei, W[4], W[5], wbuf,
                                            n0, n1, N, E);
        k_agg_out<96, false><<<qb, 256, 0, stream>>>(hs, hvb, esrc, esh, order, basei,
                                                     cnt, wbuf, attr, scs, scv,
                                                     W[6], W[7], W[8], gsb, vgb,
                                                     n0, n1, N, E);
    }
    // ---- layer 2
    k_node_mfma<64, false><<<nb2, 256, 0, stream>>>(gsb, vgb, attr,
                                                    W[11], W[12], W[9], W[10],
                                                    hs, hvb, scs, scv, N);
    for (int q = 0; q < NQ; q++) {
        const int n0 = q * Q, n1 = min(N, (q + 1) * Q);
        if (n0 >= n1) break;
        k_edge_mlp<<<emb, 256, 0, stream>>>(esc, order, basei, W[13], W[14], wbuf,
                                            n0, n1, N, E);
        k_agg_out<64, true><<<qb, 256, 0, stream>>>(hs, hvb, esrc, esh, order, basei,
                                                    cnt, wbuf, attr, scs, scv,
                                                    W[15], W[16], W[17],
                                                    (float*)d_out, nullptr,
                                                    n0, n1, N, E);
    }
}

// Round 5
// 902.609 us; speedup vs baseline: 3.5545x; 1.0047x over previous
//
#include <hip/hip_runtime.h>
#include <hip/hip_bf16.h>

#define INV_SQRT10 0.31622776601683794f
#define INV_SQRT64 0.125f
#define INV_SQRT32 0.17677669529663687f
#define INV_SQRT96 0.10206207261596575f
#define INV_SQRT3  0.5773502691896258f

typedef __attribute__((ext_vector_type(4))) float f32x4;
typedef __attribute__((ext_vector_type(8))) short bf16x8;

__device__ __forceinline__ unsigned short f2bf(float x) {
    union { float f; unsigned u; } v; v.f = x;
    unsigned r = v.u + 0x7FFF + ((v.u >> 16) & 1);
    return (unsigned short)(r >> 16);
}
__device__ __forceinline__ float bf2f(unsigned short u) {
    union { unsigned u; float f; } v; v.u = ((unsigned)u) << 16;
    return v.f;
}

// ---------------------------------------------------------------------------
// prep: node features -> bf16 (xs N x 64; xvp plane-major N x (i*32+u))
// ---------------------------------------------------------------------------
__global__ __launch_bounds__(256) void k_prep_nodes(
    const float* __restrict__ ns, const float* __restrict__ nv,
    unsigned short* __restrict__ xsb, unsigned short* __restrict__ xvpb, int N)
{
    const int gid = blockIdx.x * 256 + threadIdx.x, gs = gridDim.x * 256;
    for (int i = gid; i < N * 64; i += gs) xsb[i] = f2bf(ns[i]);
    for (int i = gid; i < N * 96; i += gs) {
        const int n = i / 96, rem = i - n * 96;
        const int ic = rem >> 5, u = rem & 31;
        xvpb[i] = f2bf(nv[(size_t)n * 96 + u * 3 + ic]);
    }
}

// ---------------------------------------------------------------------------
// prep: weights -> bf16 [c][k] layouts.
//   wsb (NC1 x 64):  c<64 -> Wl1s col c; else Wscs col c-64
//   wvb (64 x 32):   c<32 -> Wl1v col c; else Wscv col c-32
//   wfb (192 x 64):  Wfc2 transposed
// ---------------------------------------------------------------------------
template <int OS>
__global__ __launch_bounds__(256) void k_prep_w(
    const float* __restrict__ Wl1s, const float* __restrict__ Wscs,
    const float* __restrict__ Wl1v, const float* __restrict__ Wscv,
    const float* __restrict__ Wfc2,
    unsigned short* __restrict__ wsb, unsigned short* __restrict__ wvb,
    unsigned short* __restrict__ wfb)
{
    constexpr int NC1 = 64 + OS;
    const int gid = blockIdx.x * 256 + threadIdx.x, gs = gridDim.x * 256;
    for (int i = gid; i < NC1 * 64; i += gs) {
        const int c = i >> 6, k = i & 63;
        const float v = (c < 64) ? Wl1s[k * 64 + c] : Wscs[k * OS + (c - 64)];
        wsb[i] = f2bf(v);
    }
    for (int i = gid; i < 64 * 32; i += gs) {
        const int c = i >> 5, u = i & 31;
        const float v = (c < 32) ? Wl1v[u * 32 + c] : Wscv[u * 32 + (c - 32)];
        wvb[i] = f2bf(v);
    }
    for (int i = gid; i < 192 * 64; i += gs) {
        const int c = i >> 6, k = i & 63;
        wfb[i] = f2bf(Wfc2[k * 192 + c]);
    }
}

// ---------------------------------------------------------------------------
// K1: node linears, register-only MFMA. 64 nodes/block, 4 waves.
//   GEMM1: xs(64,64) @ wsb(64, NC1)     -> hs (bf16), scs (f32)
//   GEMM2: xvp-planes(192,32) @ wvb(32,64) -> hv (bf16 plane-major), scv (f32 pm)
// ---------------------------------------------------------------------------
template <int OS>
__global__ __launch_bounds__(256) void k_node_mfma(
    const unsigned short* __restrict__ xsb, const unsigned short* __restrict__ xvpb,
    const float* __restrict__ attr,
    const unsigned short* __restrict__ wsb, const unsigned short* __restrict__ wvb,
    unsigned short* __restrict__ hsb, unsigned short* __restrict__ hvbb,
    float* __restrict__ scs, float* __restrict__ scv, int N)
{
    constexpr int NC1 = 64 + OS;
    constexpr int CT1 = NC1 / 16;
    __shared__ float attr_l[64];
    const int tid = threadIdx.x;
    const int n0 = blockIdx.x * 64;
    if (tid < 64) attr_l[tid] = (n0 + tid < N) ? attr[n0 + tid] : 0.f;
    __syncthreads();
    const int wv = tid >> 6, lane = tid & 63;
    const int mrow = lane & 15, kg = lane >> 4;

    // ---- GEMM1: wave handles rows [wv*16, wv*16+16)
    {
        const int rbase = wv * 16;
        const int r = rbase + mrow;
        const int rc = min(n0 + r, N - 1);
        const bf16x8 a0 = *(const bf16x8*)(xsb + (size_t)rc * 64 + kg * 8);
        const bf16x8 a1 = *(const bf16x8*)(xsb + (size_t)rc * 64 + 32 + kg * 8);
        f32x4 acc[CT1];
        #pragma unroll
        for (int t = 0; t < CT1; t++) acc[t] = (f32x4){0.f, 0.f, 0.f, 0.f};
        #pragma unroll
        for (int t = 0; t < CT1; t++) {
            const int c = t * 16 + mrow;
            const bf16x8 b0 = *(const bf16x8*)(wsb + c * 64 + kg * 8);
            const bf16x8 b1 = *(const bf16x8*)(wsb + c * 64 + 32 + kg * 8);
            acc[t] = __builtin_amdgcn_mfma_f32_16x16x32_bf16(a0, b0, acc[t], 0, 0, 0);
            acc[t] = __builtin_amdgcn_mfma_f32_16x16x32_bf16(a1, b1, acc[t], 0, 0, 0);
        }
        #pragma unroll
        for (int t = 0; t < CT1; t++) {
            const int c = t * 16 + mrow;
            #pragma unroll
            for (int rg = 0; rg < 4; rg++) {
                const int row = rbase + kg * 4 + rg;
                const int n = n0 + row;
                if (n < N) {
                    const float v = acc[t][rg] * INV_SQRT64 * attr_l[row];
                    if (c < 64) hsb[(size_t)n * 64 + c] = f2bf(v);
                    else        scs[(size_t)n * OS + (c - 64)] = v;
                }
            }
        }
    }
    // ---- GEMM2: 12 row-tiles (rv = ic*64 + nloc), wave handles 3
    #pragma unroll
    for (int j = 0; j < 3; j++) {
        const int rbase = (wv * 3 + j) * 16;
        const int rv = rbase + mrow;
        const int ic = rv >> 6, nloc = rv & 63;
        const int nc = min(n0 + nloc, N - 1);
        const bf16x8 a = *(const bf16x8*)(xvpb + (size_t)nc * 96 + ic * 32 + kg * 8);
        f32x4 acc2[4];
        #pragma unroll
        for (int t = 0; t < 4; t++) acc2[t] = (f32x4){0.f, 0.f, 0.f, 0.f};
        #pragma unroll
        for (int t = 0; t < 4; t++) {
            const int c = t * 16 + mrow;
            const bf16x8 b = *(const bf16x8*)(wvb + c * 32 + kg * 8);
            acc2[t] = __builtin_amdgcn_mfma_f32_16x16x32_bf16(a, b, acc2[t], 0, 0, 0);
        }
        #pragma unroll
        for (int t = 0; t < 4; t++) {
            const int c = t * 16 + mrow;
            #pragma unroll
            for (int rg = 0; rg < 4; rg++) {
                const int rv2 = rbase + kg * 4 + rg;
                const int ic2 = rv2 >> 6, nl = rv2 & 63;
                const int n = n0 + nl;
                if (n < N) {
                    const float v = acc2[t][rg] * INV_SQRT32 * attr_l[nl];
                    if (c < 32) hvbb[(size_t)n * 96 + ic2 * 32 + c] = f2bf(v);
                    else        scv[(size_t)n * 96 + ic2 * 32 + (c - 32)] = v;
                }
            }
        }
    }
}

// ---------------------------------------------------------------------------
// CSR build: count -> scan -> scatter. Same graph both layers; built once.
// ---------------------------------------------------------------------------
__global__ __launch_bounds__(256) void k_count(const int* __restrict__ dst,
                                               int* __restrict__ cnt, int E)
{
    int i = blockIdx.x * 256 + threadIdx.x;
    if (i < E) atomicAdd(&cnt[dst[i]], 1);
}

__global__ __launch_bounds__(1024) void k_scan(const int* __restrict__ cnt,
                                               int* __restrict__ base, int N)
{
    __shared__ int lds[1024];
    const int t = threadIdx.x;
    const int chunk = (N + 1023) / 1024;
    const int s = t * chunk, e = min(s + chunk, N);
    int local = 0;
    for (int i = s; i < e; i++) local += cnt[i];
    lds[t] = local;
    __syncthreads();
    for (int off = 1; off < 1024; off <<= 1) {
        int v = (t >= off) ? lds[t - off] : 0;
        __syncthreads();
        lds[t] += v;
        __syncthreads();
    }
    int running = lds[t] - local;  // exclusive prefix
    for (int i = s; i < e; i++) { base[i] = running; running += cnt[i]; }
}

__global__ __launch_bounds__(256) void k_scatter(const int* __restrict__ dst,
                                                 const int* __restrict__ base,
                                                 int* __restrict__ cursor,
                                                 int* __restrict__ order, int E)
{
    int i = blockIdx.x * 256 + threadIdx.x;
    if (i < E) {
        const int d = dst[i];
        const int p = atomicAdd(&cursor[d], 1);
        order[base[d] + p] = i;
    }
}

// ---------------------------------------------------------------------------
// K2a: edge MLP, MFMA with B direct-from-global (prepped bf16 [c][k]).
//   h = silu(esc@Wfc1/sqrt10) -> bf16 LDS (swizzled)
//   w = h @ Wfc2 / sqrt64  -> packed: wbuf12[pos][c] = {w[c], w[64+c]},
//                             wbufB[pos][c] = w[128+c]
// ---------------------------------------------------------------------------
__global__ __launch_bounds__(256) void k_edge_mlp(
    const float* __restrict__ esc, const int* __restrict__ order,
    const int* __restrict__ base,
    const float* __restrict__ Wfc1, const unsigned short* __restrict__ wfb,
    unsigned* __restrict__ wbuf12, unsigned short* __restrict__ wbufB,
    int n0, int n1, int N, int E)
{
    __shared__ float esc_l[640];
    __shared__ float w1_l[640];
    __shared__ __align__(16) char hb[64 * 64 * 2];  // [row][k] bf16, swz ^((r&7)<<4)
    const int tid = threadIdx.x;
    const int lo = (n0 == 0) ? 0 : base[n0];
    const int hi = (n1 >= N) ? E : base[n1];
    const int p0 = lo + blockIdx.x * 64;
    if (p0 >= hi) return;

    for (int i = tid; i < 640; i += 256) w1_l[i] = Wfc1[i];
    for (int i = tid; i < 640; i += 256) {
        int r = i / 10, q = i - r * 10;
        int pos = p0 + r;
        int e = order[pos < hi ? pos : hi - 1];
        esc_l[i] = esc[(size_t)e * 10 + q];
    }
    __syncthreads();
    // ---- h (f32): thread -> edge r=tid>>2, cols c0=(tid&3)*16
    {
        const int r = tid >> 2, c0 = (tid & 3) << 4;
        float hval[16];
        #pragma unroll
        for (int c = 0; c < 16; c++) {
            float acc = 0.f;
            #pragma unroll
            for (int q = 0; q < 10; q++) acc += esc_l[r * 10 + q] * w1_l[q * 64 + c0 + c];
            acc *= INV_SQRT10;
            hval[c] = acc / (1.f + __expf(-acc));
        }
        unsigned pk[8];
        #pragma unroll
        for (int j = 0; j < 8; j++)
            pk[j] = (unsigned)f2bf(hval[2 * j]) | ((unsigned)f2bf(hval[2 * j + 1]) << 16);
        const int swz = (r & 7) << 4;
        const int b0 = (r << 7) + (c0 << 1);
        *(uint4*)(hb + (b0 ^ swz)) = make_uint4(pk[0], pk[1], pk[2], pk[3]);
        *(uint4*)(hb + ((b0 + 16) ^ swz)) = make_uint4(pk[4], pk[5], pk[6], pk[7]);
    }
    __syncthreads();
    // ---- MFMA: wave wv -> rows [wv*16, +16), 12 col-tiles, K=64
    const int wv = tid >> 6, lane = tid & 63;
    const int mrow = lane & 15, kgrp = lane >> 4;
    f32x4 acc[12];
    #pragma unroll
    for (int t = 0; t < 12; t++) acc[t] = (f32x4){0.f, 0.f, 0.f, 0.f};
    #pragma unroll
    for (int kc = 0; kc < 2; kc++) {
        const int r = wv * 16 + mrow;
        const int abyte = ((r << 7) + (kc << 6) + (kgrp << 4)) ^ ((r & 7) << 4);
        const bf16x8 afrag = *(const bf16x8*)(hb + abyte);
        #pragma unroll
        for (int t = 0; t < 12; t++) {
            const int c = t * 16 + mrow;
            const bf16x8 bfrag = *(const bf16x8*)(wfb + c * 64 + kc * 32 + kgrp * 8);
            acc[t] = __builtin_amdgcn_mfma_f32_16x16x32_bf16(afrag, bfrag, acc[t], 0, 0, 0);
        }
    }
    // ---- packed store
    #pragma unroll
    for (int rg = 0; rg < 4; rg++) {
        const int rloc = wv * 16 + kgrp * 4 + rg;
        const int pos = p0 + rloc;
        if (pos < hi) {
            #pragma unroll
            for (int tb = 0; tb < 4; tb++) {
                const int c = tb * 16 + mrow;
                const unsigned p12 = (unsigned)f2bf(acc[tb][rg] * INV_SQRT64)
                                   | ((unsigned)f2bf(acc[tb + 4][rg] * INV_SQRT64) << 16);
                wbuf12[(size_t)(pos - lo) * 64 + c] = p12;
                wbufB[(size_t)(pos - lo) * 64 + c] = f2bf(acc[tb + 8][rg] * INV_SQRT64);
            }
        }
    }
}

// ---------------------------------------------------------------------------
// K2b: aggregation + node finalize, fused. wave-per-dst-node over CSR.
//   bf16 gathers; layer-1 epilogue writes bf16 layer-2 inputs.
// ---------------------------------------------------------------------------
template <int OS, bool FINAL>
__global__ __launch_bounds__(256) void k_agg_out(
    const unsigned short* __restrict__ hsb, const unsigned short* __restrict__ hvbb,
    const int* __restrict__ src, const float* __restrict__ sh,
    const int* __restrict__ order, const int* __restrict__ base,
    const int* __restrict__ cnt,
    const unsigned* __restrict__ wbuf12, const unsigned short* __restrict__ wbufB,
    const float* __restrict__ attr,
    const float* __restrict__ scs, const float* __restrict__ scv,
    const float* __restrict__ W2s, const float* __restrict__ W2v,
    const float* __restrict__ Wa,
    float* __restrict__ outF,
    unsigned short* __restrict__ outSb, unsigned short* __restrict__ outVb,
    int n0, int n1, int N, int E)
{
    __shared__ float ms_l[4][96];
    __shared__ float mv_l[4][288];     // plane-major: [i*96 + u]
    __shared__ float gate_l[4][32];
    const int wave = threadIdx.x >> 6, lane = threadIdx.x & 63;
    const int n = n0 + blockIdx.x * 4 + wave;
    const bool valid = n < n1;
    const int lo = (n0 == 0) ? 0 : base[n0];

    float aS = 0.f, aSB = 0.f;
    float aV0 = 0.f, aV1 = 0.f, aV2 = 0.f;
    float aB0 = 0.f, aB1 = 0.f, aB2 = 0.f;
    int c_ = 0;
    if (valid) {
        const int b0 = base[n];
        c_ = cnt[n];
        const size_t wbase = (size_t)(b0 - lo) * 64;
        int e_nx = (c_ > 0) ? order[b0] : 0;
        for (int j = 0; j < c_; ++j) {
            const int e = e_nx;
            if (j + 1 < c_) e_nx = order[b0 + j + 1];
            const int s = e >= 0 ? src[e] : 0;
            const unsigned p12 = wbuf12[wbase + (size_t)j * 64 + lane];
            const float w1 = bf2f((unsigned short)(p12 & 0xFFFF));
            const float w2 = bf2f((unsigned short)(p12 >> 16));
            const float wB = bf2f(wbufB[wbase + (size_t)j * 64 + lane]);
            const float gs = bf2f(hsb[(size_t)s * 64 + lane]);
            float gv0 = 0.f, gv1 = 0.f, gv2 = 0.f;
            if (lane < 32) {
                gv0 = bf2f(hvbb[(size_t)s * 96 + lane]);
                gv1 = bf2f(hvbb[(size_t)s * 96 + 32 + lane]);
                gv2 = bf2f(hvbb[(size_t)s * 96 + 64 + lane]);
            }
            const float4 s4 = ((const float4*)sh)[e];
            const float gvdot = gv0 * s4.y + gv1 * s4.z + gv2 * s4.w;
            const float gvd = __shfl(gvdot, lane & 31);
            aS  += gs * s4.x * w1;
            aSB += gvd * INV_SQRT3 * wB;
            aV0 += gs * s4.y * w2;
            aV1 += gs * s4.z * w2;
            aV2 += gs * s4.w * w2;
            aB0 += gv0 * s4.x * wB;
            aB1 += gv1 * s4.x * wB;
            aB2 += gv2 * s4.x * wB;
        }
    }
    const float invd = 1.f / (float)max(c_, 1);
    if (valid) {
        ms_l[wave][lane] = aS * invd;
        if (lane >= 32) ms_l[wave][64 + (lane - 32)] = aSB * invd;
        mv_l[wave][0 * 96 + lane] = aV0 * invd;
        mv_l[wave][1 * 96 + lane] = aV1 * invd;
        mv_l[wave][2 * 96 + lane] = aV2 * invd;
        if (lane < 32) {
            mv_l[wave][0 * 96 + 64 + lane] = aB0 * invd;
            mv_l[wave][1 * 96 + 64 + lane] = aB1 * invd;
            mv_l[wave][2 * 96 + 64 + lane] = aB2 * invd;
        }
    }
    __syncthreads();
    float sA = 0.f, sB = 0.f, vA = 0.f, vB = 0.f;
    if (valid) {
        const float a = attr[n];
        float p = ms_l[wave][lane] * Wa[lane];
        if (lane < 32) p += ms_l[wave][64 + lane] * Wa[64 + lane];
        #pragma unroll
        for (int o = 32; o > 0; o >>= 1) p += __shfl_xor(p, o);
        const float alpha = p * INV_SQRT96 * a;
        const int laneB = lane & 31;
        float acc0 = 0.f, acc1 = 0.f;
        #pragma unroll 8
        for (int j = 0; j < 96; j++) {
            float m = ms_l[wave][j];
            acc0 += m * W2s[j * OS + lane];
            if (OS == 96) acc1 += m * W2s[j * 96 + 64 + laneB];
        }
        sA = scs[(size_t)n * OS + lane] + alpha * (acc0 * INV_SQRT96 * a);
        if (OS == 96) sB = scs[(size_t)n * 96 + 64 + laneB] + alpha * (acc1 * INV_SQRT96 * a);
        const int i1 = lane >> 5, k1 = lane & 31;
        float av0 = 0.f, av1 = 0.f;
        #pragma unroll 8
        for (int j = 0; j < 96; j++) {
            av0 += mv_l[wave][i1 * 96 + j] * W2v[j * 32 + k1];
            av1 += mv_l[wave][2 * 96 + j] * W2v[j * 32 + laneB];
        }
        vA = scv[(size_t)n * 96 + lane] + alpha * (av0 * INV_SQRT96 * a);
        if (lane < 32)
            vB = scv[(size_t)n * 96 + 64 + lane] + alpha * (av1 * INV_SQRT96 * a);
    }
    if (!FINAL) {
        if (valid && lane < 32) gate_l[wave][lane] = 1.f / (1.f + __expf(-sB));
    }
    __syncthreads();
    if (valid) {
        const int i1 = lane >> 5, k1 = lane & 31;
        if (FINAL) {
            float* o = outF + (size_t)n * 160;
            o[lane] = sA;
            o[64 + k1 * 3 + i1] = vA;
            if (lane < 32) o[64 + lane * 3 + 2] = vB;
        } else {
            outSb[(size_t)n * 64 + lane] = f2bf(sA / (1.f + __expf(-sA)));
            outVb[(size_t)n * 96 + lane] = f2bf(vA * gate_l[wave][k1]);
            if (lane < 32)
                outVb[(size_t)n * 96 + 64 + lane] = f2bf(vB * gate_l[wave][lane]);
        }
    }
}

// ---------------------------------------------------------------------------
extern "C" void kernel_launch(void* const* d_in, const int* in_sizes, int n_in,
                              void* d_out, int out_size, void* d_ws, size_t ws_size,
                              hipStream_t stream)
{
    const float* node_s = (const float*)d_in[0];
    const float* node_v = (const float*)d_in[1];
    const float* attr   = (const float*)d_in[2];
    const int*   esrc   = (const int*)d_in[3];
    const int*   edst   = (const int*)d_in[4];
    const float* esh    = (const float*)d_in[5];
    const float* esc    = (const float*)d_in[6];
    const float* W[18];
    for (int i = 0; i < 18; i++) W[i] = (const float*)d_in[7 + i];
    // per layer: 0 sc_s, 1 sc_v, 2 lin1_s, 3 lin1_v, 4 fc1, 5 fc2, 6 lin2_s, 7 lin2_v, 8 alpha

    const int N = in_sizes[0] / 64;
    const int E = in_sizes[3];

    char* p = (char*)d_ws;
    unsigned short* xsb  = (unsigned short*)p; p += (size_t)N * 64 * 2;
    unsigned short* xvpb = (unsigned short*)p; p += (size_t)N * 96 * 2;
    unsigned short* hsb  = (unsigned short*)p; p += (size_t)N * 64 * 2;
    unsigned short* hvbb = (unsigned short*)p; p += (size_t)N * 96 * 2;
    float* scs = (float*)p; p += (size_t)N * 96 * 4;
    float* scv = (float*)p; p += (size_t)N * 96 * 4;
    unsigned short* wsb1 = (unsigned short*)p; p += 160 * 64 * 2;
    unsigned short* wsb2 = (unsigned short*)p; p += 128 * 64 * 2;
    unsigned short* wvb1 = (unsigned short*)p; p += 64 * 32 * 2;
    unsigned short* wvb2 = (unsigned short*)p; p += 64 * 32 * 2;
    unsigned short* wfb1 = (unsigned short*)p; p += 192 * 64 * 2;
    unsigned short* wfb2 = (unsigned short*)p; p += 192 * 64 * 2;
    int* cnt    = (int*)p; p += (size_t)N * 4;
    int* cursor = (int*)p; p += (size_t)N * 4;
    int* basei  = (int*)p; p += (size_t)N * 4;
    int* order  = (int*)p; p += (size_t)E * 4;
    p = (char*)(((size_t)p + 255) & ~(size_t)255);
    unsigned* wbuf12       = (unsigned*)p;       p += (size_t)(E / 2) * 64 * 4;
    unsigned short* wbufB  = (unsigned short*)p; p += (size_t)(E / 2) * 64 * 2;

    const int nb  = (N + 63) / 64;
    const int ebk = (E + 255) / 256;
    const int NQ  = 4;
    const int Q   = (N + NQ - 1) / NQ;
    const int qb  = (Q + 3) / 4;
    // quarter edge count is ~E/4 (uniform dst); 25% slack covers skew
    const int emb = ((E / NQ) * 5 / 4 + 63) / 64;

    // ---- prep (bf16 conversions) + CSR build
    k_prep_nodes<<<2048, 256, 0, stream>>>(node_s, node_v, xsb, xvpb, N);
    k_prep_w<96><<<32, 256, 0, stream>>>(W[2], W[0], W[3], W[1], W[5], wsb1, wvb1, wfb1);
    k_prep_w<64><<<32, 256, 0, stream>>>(W[11], W[9], W[12], W[10], W[14], wsb2, wvb2, wfb2);
    hipMemsetAsync(cnt, 0, (size_t)2 * N * sizeof(int), stream);  // cnt + cursor
    k_count<<<ebk, 256, 0, stream>>>(edst, cnt, E);
    k_scan<<<1, 1024, 0, stream>>>(cnt, basei, N);
    k_scatter<<<ebk, 256, 0, stream>>>(edst, basei, cursor, order, E);

    // ---- layer 1
    k_node_mfma<96><<<nb, 256, 0, stream>>>(xsb, xvpb, attr, wsb1, wvb1,
                                            hsb, hvbb, scs, scv, N);
    for (int q = 0; q < NQ; q++) {
        const int n0 = q * Q, n1 = min(N, (q + 1) * Q);
        if (n0 >= n1) break;
        k_edge_mlp<<<emb, 256, 0, stream>>>(esc, order, basei, W[4], wfb1,
                                            wbuf12, wbufB, n0, n1, N, E);
        k_agg_out<96, false><<<qb, 256, 0, stream>>>(hsb, hvbb, esrc, esh, order, basei,
                                                     cnt, wbuf12, wbufB, attr, scs, scv,
                                                     W[6], W[7], W[8],
                                                     nullptr, xsb, xvpb,
                                                     n0, n1, N, E);
    }
    // ---- layer 2
    k_node_mfma<64><<<nb, 256, 0, stream>>>(xsb, xvpb, attr, wsb2, wvb2,
                                            hsb, hvbb, scs, scv, N);
    for (int q = 0; q < NQ; q++) {
        const int n0 = q * Q, n1 = min(N, (q + 1) * Q);
        if (n0 >= n1) break;
        k_edge_mlp<<<emb, 256, 0, stream>>>(esc, order, basei, W[13], wfb2,
                                            wbuf12, wbufB, n0, n1, N, E);
        k_agg_out<64, true><<<qb, 256, 0, stream>>>(hsb, hvbb, esrc, esh, order, basei,
                                                    cnt, wbuf12, wbufB, attr, scs, scv,
                                                    W[15], W[16], W[17],
                                                    (float*)d_out, nullptr, nullptr,
                                                    n0, n1, N, E);
    }
}

// Round 6
// 636.749 us; speedup vs baseline: 5.0385x; 1.4175x over previous
//
#include <hip/hip_runtime.h>
#include <hip/hip_bf16.h>

#define INV_SQRT10 0.31622776601683794f
#define INV_SQRT64 0.125f
#define INV_SQRT32 0.17677669529663687f
#define INV_SQRT96 0.10206207261596575f
#define INV_SQRT3  0.5773502691896258f

typedef __attribute__((ext_vector_type(4))) float f32x4;
typedef __attribute__((ext_vector_type(8))) short bf16x8;

__device__ __forceinline__ unsigned short f2bf(float x) {
    union { float f; unsigned u; } v; v.f = x;
    unsigned r = v.u + 0x7FFF + ((v.u >> 16) & 1);
    return (unsigned short)(r >> 16);
}
__device__ __forceinline__ float bf2f(unsigned short u) {
    union { unsigned u; float f; } v; v.u = ((unsigned)u) << 16;
    return v.f;
}

// ---------------------------------------------------------------------------
// prep: node features -> bf16 (xs N x 64; xvp plane-major) + degree count
// ---------------------------------------------------------------------------
__global__ __launch_bounds__(256) void k_prep_nodes(
    const float* __restrict__ ns, const float* __restrict__ nv,
    const int* __restrict__ dst,
    unsigned short* __restrict__ xsb, unsigned short* __restrict__ xvpb,
    int* __restrict__ cnt, int N, int E)
{
    const int gid = blockIdx.x * 256 + threadIdx.x, gs = gridDim.x * 256;
    for (int i = gid; i < N * 64; i += gs) xsb[i] = f2bf(ns[i]);
    for (int i = gid; i < N * 96; i += gs) {
        const int n = i / 96, rem = i - n * 96;
        const int ic = rem >> 5, u = rem & 31;
        xvpb[i] = f2bf(nv[(size_t)n * 96 + u * 3 + ic]);
    }
    for (int i = gid; i < E; i += gs) atomicAdd(&cnt[dst[i]], 1);
}

// ---------------------------------------------------------------------------
// prep: weights -> bf16 [c][k] layouts.
// ---------------------------------------------------------------------------
template <int OS>
__global__ __launch_bounds__(256) void k_prep_w(
    const float* __restrict__ Wl1s, const float* __restrict__ Wscs,
    const float* __restrict__ Wl1v, const float* __restrict__ Wscv,
    const float* __restrict__ Wfc2,
    unsigned short* __restrict__ wsb, unsigned short* __restrict__ wvb,
    unsigned short* __restrict__ wfb)
{
    constexpr int NC1 = 64 + OS;
    const int gid = blockIdx.x * 256 + threadIdx.x, gs = gridDim.x * 256;
    for (int i = gid; i < NC1 * 64; i += gs) {
        const int c = i >> 6, k = i & 63;
        const float v = (c < 64) ? Wl1s[k * 64 + c] : Wscs[k * OS + (c - 64)];
        wsb[i] = f2bf(v);
    }
    for (int i = gid; i < 64 * 32; i += gs) {
        const int c = i >> 5, u = i & 31;
        const float v = (c < 32) ? Wl1v[u * 32 + c] : Wscv[u * 32 + (c - 32)];
        wvb[i] = f2bf(v);
    }
    for (int i = gid; i < 192 * 64; i += gs) {
        const int c = i >> 6, k = i & 63;
        wfb[i] = f2bf(Wfc2[k * 192 + c]);
    }
}

// ---------------------------------------------------------------------------
// Hierarchical exclusive scan of cnt -> base.  s1: block partials;
// s2: single-block scan of partials (in-place, exclusive);
// s3: per-block intra scan + offset.
// ---------------------------------------------------------------------------
__global__ __launch_bounds__(256) void k_scan1(const int* __restrict__ cnt,
                                               int* __restrict__ partial, int N)
{
    __shared__ int lds[256];
    const int t = threadIdx.x, i = blockIdx.x * 256 + t;
    int v = (i < N) ? cnt[i] : 0;
    lds[t] = v;
    __syncthreads();
    for (int off = 128; off > 0; off >>= 1) {
        if (t < off) lds[t] += lds[t + off];
        __syncthreads();
    }
    if (t == 0) partial[blockIdx.x] = lds[0];
}

__global__ __launch_bounds__(1024) void k_scan2(int* __restrict__ partial, int NB)
{
    __shared__ int lds[1024];
    const int t = threadIdx.x;
    int v = (t < NB) ? partial[t] : 0;
    lds[t] = v;
    __syncthreads();
    for (int off = 1; off < 1024; off <<= 1) {
        int w = (t >= off) ? lds[t - off] : 0;
        __syncthreads();
        lds[t] += w;
        __syncthreads();
    }
    if (t < NB) partial[t] = lds[t] - v;   // exclusive
}

__global__ __launch_bounds__(256) void k_scan3(const int* __restrict__ cnt,
                                               const int* __restrict__ partial,
                                               int* __restrict__ base, int N)
{
    __shared__ int lds[256];
    const int t = threadIdx.x, i = blockIdx.x * 256 + t;
    int v = (i < N) ? cnt[i] : 0;
    lds[t] = v;
    __syncthreads();
    for (int off = 1; off < 256; off <<= 1) {
        int w = (t >= off) ? lds[t - off] : 0;
        __syncthreads();
        lds[t] += w;
        __syncthreads();
    }
    if (i < N) base[i] = partial[blockIdx.x] + lds[t] - v;
}

// ---------------------------------------------------------------------------
// scatter: materialize CSR-ordered src / sh / esc.
// ---------------------------------------------------------------------------
__global__ __launch_bounds__(256) void k_scatter(
    const int* __restrict__ src, const int* __restrict__ dst,
    const float* __restrict__ sh, const float* __restrict__ esc,
    const int* __restrict__ base, int* __restrict__ cursor,
    int* __restrict__ src_ord, float4* __restrict__ sh_ord,
    float* __restrict__ esc_ord, int E)
{
    int i = blockIdx.x * 256 + threadIdx.x;
    if (i < E) {
        const int d = dst[i];
        const int pos = base[d] + atomicAdd(&cursor[d], 1);
        src_ord[pos] = src[i];
        sh_ord[pos] = ((const float4*)sh)[i];
        const float* ep = esc + (size_t)i * 10;
        float* eo = esc_ord + (size_t)pos * 10;
        #pragma unroll
        for (int q = 0; q < 10; q++) eo[q] = ep[q];
    }
}

// ---------------------------------------------------------------------------
// K1: node linears, register-only MFMA. 64 nodes/block, 4 waves.
// ---------------------------------------------------------------------------
template <int OS>
__global__ __launch_bounds__(256) void k_node_mfma(
    const unsigned short* __restrict__ xsb, const unsigned short* __restrict__ xvpb,
    const float* __restrict__ attr,
    const unsigned short* __restrict__ wsb, const unsigned short* __restrict__ wvb,
    unsigned short* __restrict__ hsb, unsigned short* __restrict__ hvbb,
    float* __restrict__ scs, float* __restrict__ scv, int N)
{
    constexpr int NC1 = 64 + OS;
    constexpr int CT1 = NC1 / 16;
    __shared__ float attr_l[64];
    const int tid = threadIdx.x;
    const int n0 = blockIdx.x * 64;
    if (tid < 64) attr_l[tid] = (n0 + tid < N) ? attr[n0 + tid] : 0.f;
    __syncthreads();
    const int wv = tid >> 6, lane = tid & 63;
    const int mrow = lane & 15, kg = lane >> 4;

    {
        const int rbase = wv * 16;
        const int r = rbase + mrow;
        const int rc = min(n0 + r, N - 1);
        const bf16x8 a0 = *(const bf16x8*)(xsb + (size_t)rc * 64 + kg * 8);
        const bf16x8 a1 = *(const bf16x8*)(xsb + (size_t)rc * 64 + 32 + kg * 8);
        f32x4 acc[CT1];
        #pragma unroll
        for (int t = 0; t < CT1; t++) acc[t] = (f32x4){0.f, 0.f, 0.f, 0.f};
        #pragma unroll
        for (int t = 0; t < CT1; t++) {
            const int c = t * 16 + mrow;
            const bf16x8 b0 = *(const bf16x8*)(wsb + c * 64 + kg * 8);
            const bf16x8 b1 = *(const bf16x8*)(wsb + c * 64 + 32 + kg * 8);
            acc[t] = __builtin_amdgcn_mfma_f32_16x16x32_bf16(a0, b0, acc[t], 0, 0, 0);
            acc[t] = __builtin_amdgcn_mfma_f32_16x16x32_bf16(a1, b1, acc[t], 0, 0, 0);
        }
        #pragma unroll
        for (int t = 0; t < CT1; t++) {
            const int c = t * 16 + mrow;
            #pragma unroll
            for (int rg = 0; rg < 4; rg++) {
                const int row = rbase + kg * 4 + rg;
                const int n = n0 + row;
                if (n < N) {
                    const float v = acc[t][rg] * INV_SQRT64 * attr_l[row];
                    if (c < 64) hsb[(size_t)n * 64 + c] = f2bf(v);
                    else        scs[(size_t)n * OS + (c - 64)] = v;
                }
            }
        }
    }
    #pragma unroll
    for (int j = 0; j < 3; j++) {
        const int rbase = (wv * 3 + j) * 16;
        const int rv = rbase + mrow;
        const int ic = rv >> 6, nloc = rv & 63;
        const int nc = min(n0 + nloc, N - 1);
        const bf16x8 a = *(const bf16x8*)(xvpb + (size_t)nc * 96 + ic * 32 + kg * 8);
        f32x4 acc2[4];
        #pragma unroll
        for (int t = 0; t < 4; t++) acc2[t] = (f32x4){0.f, 0.f, 0.f, 0.f};
        #pragma unroll
        for (int t = 0; t < 4; t++) {
            const int c = t * 16 + mrow;
            const bf16x8 b = *(const bf16x8*)(wvb + c * 32 + kg * 8);
            acc2[t] = __builtin_amdgcn_mfma_f32_16x16x32_bf16(a, b, acc2[t], 0, 0, 0);
        }
        #pragma unroll
        for (int t = 0; t < 4; t++) {
            const int c = t * 16 + mrow;
            #pragma unroll
            for (int rg = 0; rg < 4; rg++) {
                const int rv2 = rbase + kg * 4 + rg;
                const int ic2 = rv2 >> 6, nl = rv2 & 63;
                const int n = n0 + nl;
                if (n < N) {
                    const float v = acc2[t][rg] * INV_SQRT32 * attr_l[nl];
                    if (c < 32) hvbb[(size_t)n * 96 + ic2 * 32 + c] = f2bf(v);
                    else        scv[(size_t)n * 96 + ic2 * 32 + (c - 32)] = v;
                }
            }
        }
    }
}

// ---------------------------------------------------------------------------
// K2a: edge MLP; esc read coalesced from esc_ord; B direct-from-global.
// ---------------------------------------------------------------------------
__global__ __launch_bounds__(256) void k_edge_mlp(
    const float* __restrict__ esc_ord, const int* __restrict__ base,
    const float* __restrict__ Wfc1, const unsigned short* __restrict__ wfb,
    unsigned* __restrict__ wbuf12, unsigned short* __restrict__ wbufB,
    int n0, int n1, int N, int E, int cap)
{
    __shared__ float esc_l[640];
    __shared__ float w1_l[640];
    __shared__ __align__(16) char hb[64 * 64 * 2];  // [row][k] bf16, swz ^((r&7)<<4)
    const int tid = threadIdx.x;
    const int lo = (n0 == 0) ? 0 : base[n0];
    const int hi = (n1 >= N) ? E : base[n1];
    const int p0 = lo + blockIdx.x * 64;
    if (p0 >= hi) return;

    for (int i = tid; i < 640; i += 256) w1_l[i] = Wfc1[i];
    {
        const size_t emax = (size_t)E * 10 - 1;
        for (int i = tid; i < 640; i += 256) {
            size_t idx = (size_t)p0 * 10 + i;
            esc_l[i] = esc_ord[idx > emax ? emax : idx];
        }
    }
    __syncthreads();
    // ---- h (f32): thread -> edge r=tid>>2, cols c0=(tid&3)*16
    {
        const int r = tid >> 2, c0 = (tid & 3) << 4;
        float hval[16];
        #pragma unroll
        for (int c = 0; c < 16; c++) {
            float acc = 0.f;
            #pragma unroll
            for (int q = 0; q < 10; q++) acc += esc_l[r * 10 + q] * w1_l[q * 64 + c0 + c];
            acc *= INV_SQRT10;
            hval[c] = acc / (1.f + __expf(-acc));
        }
        unsigned pk[8];
        #pragma unroll
        for (int j = 0; j < 8; j++)
            pk[j] = (unsigned)f2bf(hval[2 * j]) | ((unsigned)f2bf(hval[2 * j + 1]) << 16);
        const int swz = (r & 7) << 4;
        const int b0 = (r << 7) + (c0 << 1);
        *(uint4*)(hb + (b0 ^ swz)) = make_uint4(pk[0], pk[1], pk[2], pk[3]);
        *(uint4*)(hb + ((b0 + 16) ^ swz)) = make_uint4(pk[4], pk[5], pk[6], pk[7]);
    }
    __syncthreads();
    // ---- MFMA: wave wv -> rows [wv*16, +16), 12 col-tiles, K=64
    const int wv = tid >> 6, lane = tid & 63;
    const int mrow = lane & 15, kgrp = lane >> 4;
    f32x4 acc[12];
    #pragma unroll
    for (int t = 0; t < 12; t++) acc[t] = (f32x4){0.f, 0.f, 0.f, 0.f};
    #pragma unroll
    for (int kc = 0; kc < 2; kc++) {
        const int r = wv * 16 + mrow;
        const int abyte = ((r << 7) + (kc << 6) + (kgrp << 4)) ^ ((r & 7) << 4);
        const bf16x8 afrag = *(const bf16x8*)(hb + abyte);
        #pragma unroll
        for (int t = 0; t < 12; t++) {
            const int c = t * 16 + mrow;
            const bf16x8 bfrag = *(const bf16x8*)(wfb + c * 64 + kc * 32 + kgrp * 8);
            acc[t] = __builtin_amdgcn_mfma_f32_16x16x32_bf16(afrag, bfrag, acc[t], 0, 0, 0);
        }
    }
    // ---- packed store
    #pragma unroll
    for (int rg = 0; rg < 4; rg++) {
        const int rloc = wv * 16 + kgrp * 4 + rg;
        const int pos = p0 + rloc;
        if (pos < hi && (pos - lo) < cap) {
            #pragma unroll
            for (int tb = 0; tb < 4; tb++) {
                const int c = tb * 16 + mrow;
                const unsigned p12 = (unsigned)f2bf(acc[tb][rg] * INV_SQRT64)
                                   | ((unsigned)f2bf(acc[tb + 4][rg] * INV_SQRT64) << 16);
                wbuf12[(size_t)(pos - lo) * 64 + c] = p12;
                wbufB[(size_t)(pos - lo) * 64 + c] = f2bf(acc[tb + 8][rg] * INV_SQRT64);
            }
        }
    }
}

// ---------------------------------------------------------------------------
// K2b: aggregation + node finalize, fused. wave-per-dst-node over CSR.
// ---------------------------------------------------------------------------
template <int OS, bool FINAL>
__global__ __launch_bounds__(256) void k_agg_out(
    const unsigned short* __restrict__ hsb, const unsigned short* __restrict__ hvbb,
    const int* __restrict__ src_ord, const float4* __restrict__ sh_ord,
    const int* __restrict__ base, const int* __restrict__ cnt,
    const unsigned* __restrict__ wbuf12, const unsigned short* __restrict__ wbufB,
    const float* __restrict__ attr,
    const float* __restrict__ scs, const float* __restrict__ scv,
    const float* __restrict__ W2s, const float* __restrict__ W2v,
    const float* __restrict__ Wa,
    float* __restrict__ outF,
    unsigned short* __restrict__ outSb, unsigned short* __restrict__ outVb,
    int n0, int n1, int N, int E)
{
    __shared__ float ms_l[4][96];
    __shared__ float mv_l[4][288];     // plane-major: [i*96 + u]
    __shared__ float gate_l[4][32];
    const int wave = threadIdx.x >> 6, lane = threadIdx.x & 63;
    const int n = n0 + blockIdx.x * 4 + wave;
    const bool valid = n < n1;
    const int lo = (n0 == 0) ? 0 : base[n0];

    float aS = 0.f, aSB = 0.f;
    float aV0 = 0.f, aV1 = 0.f, aV2 = 0.f;
    float aB0 = 0.f, aB1 = 0.f, aB2 = 0.f;
    int c_ = 0;
    if (valid) {
        const int b0 = base[n];
        c_ = cnt[n];
        const size_t wb = (size_t)(b0 - lo) * 64;
        int s_nx = (c_ > 0) ? src_ord[b0] : 0;
        for (int j = 0; j < c_; ++j) {
            const int s = s_nx;
            if (j + 1 < c_) s_nx = src_ord[b0 + j + 1];
            const unsigned p12 = wbuf12[wb + (size_t)j * 64 + lane];
            const float w1 = bf2f((unsigned short)(p12 & 0xFFFF));
            const float w2 = bf2f((unsigned short)(p12 >> 16));
            const float wB = bf2f(wbufB[wb + (size_t)j * 64 + lane]);
            const float gs = bf2f(hsb[(size_t)s * 64 + lane]);
            float gv0 = 0.f, gv1 = 0.f, gv2 = 0.f;
            if (lane < 32) {
                gv0 = bf2f(hvbb[(size_t)s * 96 + lane]);
                gv1 = bf2f(hvbb[(size_t)s * 96 + 32 + lane]);
                gv2 = bf2f(hvbb[(size_t)s * 96 + 64 + lane]);
            }
            const float4 s4 = sh_ord[b0 + j];
            const float gvdot = gv0 * s4.y + gv1 * s4.z + gv2 * s4.w;
            const float gvd = __shfl(gvdot, lane & 31);
            aS  += gs * s4.x * w1;
            aSB += gvd * INV_SQRT3 * wB;
            aV0 += gs * s4.y * w2;
            aV1 += gs * s4.z * w2;
            aV2 += gs * s4.w * w2;
            aB0 += gv0 * s4.x * wB;
            aB1 += gv1 * s4.x * wB;
            aB2 += gv2 * s4.x * wB;
        }
    }
    const float invd = 1.f / (float)max(c_, 1);
    if (valid) {
        ms_l[wave][lane] = aS * invd;
        if (lane >= 32) ms_l[wave][64 + (lane - 32)] = aSB * invd;
        mv_l[wave][0 * 96 + lane] = aV0 * invd;
        mv_l[wave][1 * 96 + lane] = aV1 * invd;
        mv_l[wave][2 * 96 + lane] = aV2 * invd;
        if (lane < 32) {
            mv_l[wave][0 * 96 + 64 + lane] = aB0 * invd;
            mv_l[wave][1 * 96 + 64 + lane] = aB1 * invd;
            mv_l[wave][2 * 96 + 64 + lane] = aB2 * invd;
        }
    }
    __syncthreads();
    float sA = 0.f, sB = 0.f, vA = 0.f, vB = 0.f;
    if (valid) {
        const float a = attr[n];
        float p = ms_l[wave][lane] * Wa[lane];
        if (lane < 32) p += ms_l[wave][64 + lane] * Wa[64 + lane];
        #pragma unroll
        for (int o = 32; o > 0; o >>= 1) p += __shfl_xor(p, o);
        const float alpha = p * INV_SQRT96 * a;
        const int laneB = lane & 31;
        float acc0 = 0.f, acc1 = 0.f;
        #pragma unroll 8
        for (int j = 0; j < 96; j++) {
            float m = ms_l[wave][j];
            acc0 += m * W2s[j * OS + lane];
            if (OS == 96) acc1 += m * W2s[j * 96 + 64 + laneB];
        }
        sA = scs[(size_t)n * OS + lane] + alpha * (acc0 * INV_SQRT96 * a);
        if (OS == 96) sB = scs[(size_t)n * 96 + 64 + laneB] + alpha * (acc1 * INV_SQRT96 * a);
        const int i1 = lane >> 5, k1 = lane & 31;
        float av0 = 0.f, av1 = 0.f;
        #pragma unroll 8
        for (int j = 0; j < 96; j++) {
            av0 += mv_l[wave][i1 * 96 + j] * W2v[j * 32 + k1];
            av1 += mv_l[wave][2 * 96 + j] * W2v[j * 32 + laneB];
        }
        vA = scv[(size_t)n * 96 + lane] + alpha * (av0 * INV_SQRT96 * a);
        if (lane < 32)
            vB = scv[(size_t)n * 96 + 64 + lane] + alpha * (av1 * INV_SQRT96 * a);
    }
    if (!FINAL) {
        if (valid && lane < 32) gate_l[wave][lane] = 1.f / (1.f + __expf(-sB));
    }
    __syncthreads();
    if (valid) {
        const int i1 = lane >> 5, k1 = lane & 31;
        if (FINAL) {
            float* o = outF + (size_t)n * 160;
            o[lane] = sA;
            o[64 + k1 * 3 + i1] = vA;
            if (lane < 32) o[64 + lane * 3 + 2] = vB;
        } else {
            outSb[(size_t)n * 64 + lane] = f2bf(sA / (1.f + __expf(-sA)));
            outVb[(size_t)n * 96 + lane] = f2bf(vA * gate_l[wave][k1]);
            if (lane < 32)
                outVb[(size_t)n * 96 + 64 + lane] = f2bf(vB * gate_l[wave][lane]);
        }
    }
}

// ---------------------------------------------------------------------------
extern "C" void kernel_launch(void* const* d_in, const int* in_sizes, int n_in,
                              void* d_out, int out_size, void* d_ws, size_t ws_size,
                              hipStream_t stream)
{
    const float* node_s = (const float*)d_in[0];
    const float* node_v = (const float*)d_in[1];
    const float* attr   = (const float*)d_in[2];
    const int*   esrc   = (const int*)d_in[3];
    const int*   edst   = (const int*)d_in[4];
    const float* esh    = (const float*)d_in[5];
    const float* esc    = (const float*)d_in[6];
    const float* W[18];
    for (int i = 0; i < 18; i++) W[i] = (const float*)d_in[7 + i];
    // per layer: 0 sc_s, 1 sc_v, 2 lin1_s, 3 lin1_v, 4 fc1, 5 fc2, 6 lin2_s, 7 lin2_v, 8 alpha

    const int N = in_sizes[0] / 64;
    const int E = in_sizes[3];
    const int NB = (N + 255) / 256;

    char* p = (char*)d_ws;
    unsigned short* xsb  = (unsigned short*)p; p += (size_t)N * 64 * 2;
    unsigned short* xvpb = (unsigned short*)p; p += (size_t)N * 96 * 2;
    unsigned short* hsb  = (unsigned short*)p; p += (size_t)N * 64 * 2;
    unsigned short* hvbb = (unsigned short*)p; p += (size_t)N * 96 * 2;
    float* scs = (float*)p; p += (size_t)N * 96 * 4;
    float* scv = (float*)p; p += (size_t)N * 96 * 4;
    unsigned short* wsb1 = (unsigned short*)p; p += 160 * 64 * 2;
    unsigned short* wsb2 = (unsigned short*)p; p += 128 * 64 * 2;
    unsigned short* wvb1 = (unsigned short*)p; p += 64 * 32 * 2;
    unsigned short* wvb2 = (unsigned short*)p; p += 64 * 32 * 2;
    unsigned short* wfb1 = (unsigned short*)p; p += 192 * 64 * 2;
    unsigned short* wfb2 = (unsigned short*)p; p += 192 * 64 * 2;
    int* cnt    = (int*)p; p += (size_t)N * 4;
    int* cursor = (int*)p; p += (size_t)N * 4;
    int* basei  = (int*)p; p += (size_t)N * 4;
    int* partial = (int*)p; p += (size_t)NB * 4;
    p = (char*)(((size_t)p + 255) & ~(size_t)255);
    int* src_ord = (int*)p; p += (size_t)E * 4;
    p = (char*)(((size_t)p + 15) & ~(size_t)15);
    float4* sh_ord = (float4*)p; p += (size_t)E * 16;
    float* esc_ord = (float*)p; p += (size_t)E * 40;
    p = (char*)(((size_t)p + 255) & ~(size_t)255);
    const size_t used_fixed = (size_t)(p - (char*)d_ws);

    // adaptive quartering: pick smallest NQ whose wbuf fits
    int NQ = 4;
    size_t cap = 0;
    {
        const int cands[3] = {1, 2, 4};
        for (int ci = 0; ci < 3; ci++) {
            const int c = cands[ci];
            size_t cc = (c == 1) ? (size_t)E : ((size_t)E / c) * 9 / 8 + 256;
            if (used_fixed + cc * 384 <= ws_size) { NQ = c; cap = cc; break; }
        }
        if (cap == 0) { NQ = 4; cap = ((size_t)E / 4) * 9 / 8 + 256; }
    }
    unsigned* wbuf12      = (unsigned*)p;       p += cap * 256;
    unsigned short* wbufB = (unsigned short*)p; p += cap * 128;

    const int nb  = (N + 63) / 64;
    const int ebk = (E + 255) / 256;
    const int Q   = (N + NQ - 1) / NQ;
    const int qb  = (Q + 3) / 4;
    const int emb = (int)((cap + 63) / 64);

    // ---- prep + CSR build
    hipMemsetAsync(cnt, 0, (size_t)2 * N * sizeof(int), stream);  // cnt + cursor
    k_prep_nodes<<<2048, 256, 0, stream>>>(node_s, node_v, edst, xsb, xvpb, cnt, N, E);
    k_prep_w<96><<<32, 256, 0, stream>>>(W[2], W[0], W[3], W[1], W[5], wsb1, wvb1, wfb1);
    k_prep_w<64><<<32, 256, 0, stream>>>(W[11], W[9], W[12], W[10], W[14], wsb2, wvb2, wfb2);
    k_scan1<<<NB, 256, 0, stream>>>(cnt, partial, N);
    k_scan2<<<1, 1024, 0, stream>>>(partial, NB);
    k_scan3<<<NB, 256, 0, stream>>>(cnt, partial, basei, N);
    k_scatter<<<ebk, 256, 0, stream>>>(esrc, edst, esh, esc, basei, cursor,
                                       src_ord, sh_ord, esc_ord, E);

    // ---- layer 1
    k_node_mfma<96><<<nb, 256, 0, stream>>>(xsb, xvpb, attr, wsb1, wvb1,
                                            hsb, hvbb, scs, scv, N);
    for (int q = 0; q < NQ; q++) {
        const int n0 = q * Q, n1 = min(N, (q + 1) * Q);
        if (n0 >= n1) break;
        k_edge_mlp<<<emb, 256, 0, stream>>>(esc_ord, basei, W[4], wfb1,
                                            wbuf12, wbufB, n0, n1, N, E, (int)cap);
        k_agg_out<96, false><<<qb, 256, 0, stream>>>(hsb, hvbb, src_ord, sh_ord, basei,
                                                     cnt, wbuf12, wbufB, attr, scs, scv,
                                                     W[6], W[7], W[8],
                                                     nullptr, xsb, xvpb,
                                                     n0, n1, N, E);
    }
    // ---- layer 2
    k_node_mfma<64><<<nb, 256, 0, stream>>>(xsb, xvpb, attr, wsb2, wvb2,
                                            hsb, hvbb, scs, scv, N);
    for (int q = 0; q < NQ; q++) {
        const int n0 = q * Q, n1 = min(N, (q + 1) * Q);
        if (n0 >= n1) break;
        k_edge_mlp<<<emb, 256, 0, stream>>>(esc_ord, basei, W[13], wfb2,
                                            wbuf12, wbufB, n0, n1, N, E, (int)cap);
        k_agg_out<64, true><<<qb, 256, 0, stream>>>(hsb, hvbb, src_ord, sh_ord, basei,
                                                    cnt, wbuf12, wbufB, attr, scs, scv,
                                                    W[15], W[16], W[17],
                                                    (float*)d_out, nullptr, nullptr,
                                                    n0, n1, N, E);
    }
}

// Round 7
// 576.631 us; speedup vs baseline: 5.5639x; 1.1043x over previous
//
#include <hip/hip_runtime.h>
#include <hip/hip_bf16.h>

#define INV_SQRT10 0.31622776601683794f
#define INV_SQRT64 0.125f
#define INV_SQRT32 0.17677669529663687f
#define INV_SQRT96 0.10206207261596575f
#define INV_SQRT3  0.5773502691896258f

typedef __attribute__((ext_vector_type(4))) float f32x4;
typedef __attribute__((ext_vector_type(8))) short bf16x8;

__device__ __forceinline__ unsigned short f2bf(float x) {
    union { float f; unsigned u; } v; v.f = x;
    unsigned r = v.u + 0x7FFF + ((v.u >> 16) & 1);
    return (unsigned short)(r >> 16);
}
__device__ __forceinline__ float bf2f(unsigned short u) {
    union { unsigned u; float f; } v; v.u = ((unsigned)u) << 16;
    return v.f;
}

// ---------------------------------------------------------------------------
// prep: node features -> bf16 (xs N x 64; xvp plane-major) + degree count
// ---------------------------------------------------------------------------
__global__ __launch_bounds__(256) void k_prep_nodes(
    const float* __restrict__ ns, const float* __restrict__ nv,
    const int* __restrict__ dst,
    unsigned short* __restrict__ xsb, unsigned short* __restrict__ xvpb,
    int* __restrict__ cnt, int N, int E)
{
    const int gid = blockIdx.x * 256 + threadIdx.x, gs = gridDim.x * 256;
    for (int i = gid; i < N * 64; i += gs) xsb[i] = f2bf(ns[i]);
    for (int i = gid; i < N * 96; i += gs) {
        const int n = i / 96, rem = i - n * 96;
        const int ic = rem >> 5, u = rem & 31;
        xvpb[i] = f2bf(nv[(size_t)n * 96 + u * 3 + ic]);
    }
    for (int i = gid; i < E; i += gs) atomicAdd(&cnt[dst[i]], 1);
}

// ---------------------------------------------------------------------------
// prep: weights -> bf16 panels.
//   wsb (NC1 x 64):   c<64 -> Wl1s col c; else Wscs col c-64        (lin1 K=64)
//   wvb (64 x 32):    c<32 -> Wl1v col c; else Wscv col c-32        (lin1v K=32)
//   wfb (192 x 64):   Wfc2^T                                         (edge K=64)
//   wob (PC1 x 96):   c<OS -> W2s col c; c==OS -> Wa; else 0        (lin2 K=96)
//   wv2b (32 x 96):   W2v^T                                          (lin2v K=96)
// ---------------------------------------------------------------------------
template <int OS>
__global__ __launch_bounds__(256) void k_prep_w(
    const float* __restrict__ Wl1s, const float* __restrict__ Wscs,
    const float* __restrict__ Wl1v, const float* __restrict__ Wscv,
    const float* __restrict__ Wfc2,
    const float* __restrict__ W2s, const float* __restrict__ W2v,
    const float* __restrict__ Wa,
    unsigned short* __restrict__ wsb, unsigned short* __restrict__ wvb,
    unsigned short* __restrict__ wfb,
    unsigned short* __restrict__ wob, unsigned short* __restrict__ wv2b)
{
    constexpr int NC1 = 64 + OS;
    constexpr int PC1 = ((OS + 16 + 15) / 16) * 16;   // 112 (OS=96) / 80 (OS=64)
    const int gid = blockIdx.x * 256 + threadIdx.x, gs = gridDim.x * 256;
    for (int i = gid; i < NC1 * 64; i += gs) {
        const int c = i >> 6, k = i & 63;
        const float v = (c < 64) ? Wl1s[k * 64 + c] : Wscs[k * OS + (c - 64)];
        wsb[i] = f2bf(v);
    }
    for (int i = gid; i < 64 * 32; i += gs) {
        const int c = i >> 5, u = i & 31;
        const float v = (c < 32) ? Wl1v[u * 32 + c] : Wscv[u * 32 + (c - 32)];
        wvb[i] = f2bf(v);
    }
    for (int i = gid; i < 192 * 64; i += gs) {
        const int c = i >> 6, k = i & 63;
        wfb[i] = f2bf(Wfc2[k * 192 + c]);
    }
    for (int i = gid; i < PC1 * 96; i += gs) {
        const int c = i / 96, u = i - c * 96;
        float v = 0.f;
        if (c < OS) v = W2s[u * OS + c];
        else if (c == OS) v = Wa[u];
        wob[i] = f2bf(v);
    }
    for (int i = gid; i < 32 * 96; i += gs) {
        const int c = i / 96, u = i - c * 96;
        wv2b[i] = f2bf(W2v[u * 32 + c]);
    }
}

// ---------------------------------------------------------------------------
// Hierarchical exclusive scan of cnt -> base.
// ---------------------------------------------------------------------------
__global__ __launch_bounds__(256) void k_scan1(const int* __restrict__ cnt,
                                               int* __restrict__ partial, int N)
{
    __shared__ int lds[256];
    const int t = threadIdx.x, i = blockIdx.x * 256 + t;
    int v = (i < N) ? cnt[i] : 0;
    lds[t] = v;
    __syncthreads();
    for (int off = 128; off > 0; off >>= 1) {
        if (t < off) lds[t] += lds[t + off];
        __syncthreads();
    }
    if (t == 0) partial[blockIdx.x] = lds[0];
}

__global__ __launch_bounds__(1024) void k_scan2(int* __restrict__ partial, int NB)
{
    __shared__ int lds[1024];
    const int t = threadIdx.x;
    int v = (t < NB) ? partial[t] : 0;
    lds[t] = v;
    __syncthreads();
    for (int off = 1; off < 1024; off <<= 1) {
        int w = (t >= off) ? lds[t - off] : 0;
        __syncthreads();
        lds[t] += w;
        __syncthreads();
    }
    if (t < NB) partial[t] = lds[t] - v;   // exclusive
}

__global__ __launch_bounds__(256) void k_scan3(const int* __restrict__ cnt,
                                               const int* __restrict__ partial,
                                               int* __restrict__ base, int N)
{
    __shared__ int lds[256];
    const int t = threadIdx.x, i = blockIdx.x * 256 + t;
    int v = (i < N) ? cnt[i] : 0;
    lds[t] = v;
    __syncthreads();
    for (int off = 1; off < 256; off <<= 1) {
        int w = (t >= off) ? lds[t - off] : 0;
        __syncthreads();
        lds[t] += w;
        __syncthreads();
    }
    if (i < N) base[i] = partial[blockIdx.x] + lds[t] - v;
}

// ---------------------------------------------------------------------------
// scatter: materialize CSR-ordered src / sh / esc.
// ---------------------------------------------------------------------------
__global__ __launch_bounds__(256) void k_scatter(
    const int* __restrict__ src, const int* __restrict__ dst,
    const float* __restrict__ sh, const float* __restrict__ esc,
    const int* __restrict__ base, int* __restrict__ cursor,
    int* __restrict__ src_ord, float4* __restrict__ sh_ord,
    float* __restrict__ esc_ord, int E)
{
    int i = blockIdx.x * 256 + threadIdx.x;
    if (i < E) {
        const int d = dst[i];
        const int pos = base[d] + atomicAdd(&cursor[d], 1);
        src_ord[pos] = src[i];
        sh_ord[pos] = ((const float4*)sh)[i];
        const float* ep = esc + (size_t)i * 10;
        float* eo = esc_ord + (size_t)pos * 10;
        #pragma unroll
        for (int q = 0; q < 10; q++) eo[q] = ep[q];
    }
}

// ---------------------------------------------------------------------------
// K1: node linears, register-only MFMA. 64 nodes/block, 4 waves.
// ---------------------------------------------------------------------------
template <int OS>
__global__ __launch_bounds__(256) void k_node_mfma(
    const unsigned short* __restrict__ xsb, const unsigned short* __restrict__ xvpb,
    const float* __restrict__ attr,
    const unsigned short* __restrict__ wsb, const unsigned short* __restrict__ wvb,
    unsigned short* __restrict__ hsb, unsigned short* __restrict__ hvbb,
    float* __restrict__ scs, float* __restrict__ scv, int N)
{
    constexpr int NC1 = 64 + OS;
    constexpr int CT1 = NC1 / 16;
    __shared__ float attr_l[64];
    const int tid = threadIdx.x;
    const int n0 = blockIdx.x * 64;
    if (tid < 64) attr_l[tid] = (n0 + tid < N) ? attr[n0 + tid] : 0.f;
    __syncthreads();
    const int wv = tid >> 6, lane = tid & 63;
    const int mrow = lane & 15, kg = lane >> 4;

    {
        const int rbase = wv * 16;
        const int r = rbase + mrow;
        const int rc = min(n0 + r, N - 1);
        const bf16x8 a0 = *(const bf16x8*)(xsb + (size_t)rc * 64 + kg * 8);
        const bf16x8 a1 = *(const bf16x8*)(xsb + (size_t)rc * 64 + 32 + kg * 8);
        f32x4 acc[CT1];
        #pragma unroll
        for (int t = 0; t < CT1; t++) acc[t] = (f32x4){0.f, 0.f, 0.f, 0.f};
        #pragma unroll
        for (int t = 0; t < CT1; t++) {
            const int c = t * 16 + mrow;
            const bf16x8 b0 = *(const bf16x8*)(wsb + c * 64 + kg * 8);
            const bf16x8 b1 = *(const bf16x8*)(wsb + c * 64 + 32 + kg * 8);
            acc[t] = __builtin_amdgcn_mfma_f32_16x16x32_bf16(a0, b0, acc[t], 0, 0, 0);
            acc[t] = __builtin_amdgcn_mfma_f32_16x16x32_bf16(a1, b1, acc[t], 0, 0, 0);
        }
        #pragma unroll
        for (int t = 0; t < CT1; t++) {
            const int c = t * 16 + mrow;
            #pragma unroll
            for (int rg = 0; rg < 4; rg++) {
                const int row = rbase + kg * 4 + rg;
                const int n = n0 + row;
                if (n < N) {
                    const float v = acc[t][rg] * INV_SQRT64 * attr_l[row];
                    if (c < 64) hsb[(size_t)n * 64 + c] = f2bf(v);
                    else        scs[(size_t)n * OS + (c - 64)] = v;
                }
            }
        }
    }
    #pragma unroll
    for (int j = 0; j < 3; j++) {
        const int rbase = (wv * 3 + j) * 16;
        const int rv = rbase + mrow;
        const int ic = rv >> 6, nloc = rv & 63;
        const int nc = min(n0 + nloc, N - 1);
        const bf16x8 a = *(const bf16x8*)(xvpb + (size_t)nc * 96 + ic * 32 + kg * 8);
        f32x4 acc2[4];
        #pragma unroll
        for (int t = 0; t < 4; t++) acc2[t] = (f32x4){0.f, 0.f, 0.f, 0.f};
        #pragma unroll
        for (int t = 0; t < 4; t++) {
            const int c = t * 16 + mrow;
            const bf16x8 b = *(const bf16x8*)(wvb + c * 32 + kg * 8);
            acc2[t] = __builtin_amdgcn_mfma_f32_16x16x32_bf16(a, b, acc2[t], 0, 0, 0);
        }
        #pragma unroll
        for (int t = 0; t < 4; t++) {
            const int c = t * 16 + mrow;
            #pragma unroll
            for (int rg = 0; rg < 4; rg++) {
                const int rv2 = rbase + kg * 4 + rg;
                const int ic2 = rv2 >> 6, nl = rv2 & 63;
                const int n = n0 + nl;
                if (n < N) {
                    const float v = acc2[t][rg] * INV_SQRT32 * attr_l[nl];
                    if (c < 32) hvbb[(size_t)n * 96 + ic2 * 32 + c] = f2bf(v);
                    else        scv[(size_t)n * 96 + ic2 * 32 + (c - 32)] = v;
                }
            }
        }
    }
}

// ---------------------------------------------------------------------------
// K2a: edge MLP; esc read coalesced from esc_ord; B direct-from-global.
// ---------------------------------------------------------------------------
__global__ __launch_bounds__(256) void k_edge_mlp(
    const float* __restrict__ esc_ord, const int* __restrict__ base,
    const float* __restrict__ Wfc1, const unsigned short* __restrict__ wfb,
    unsigned* __restrict__ wbuf12, unsigned short* __restrict__ wbufB,
    int n0, int n1, int N, int E, int cap)
{
    __shared__ float esc_l[640];
    __shared__ float w1_l[640];
    __shared__ __align__(16) char hb[64 * 64 * 2];  // [row][k] bf16, swz ^((r&7)<<4)
    const int tid = threadIdx.x;
    const int lo = (n0 == 0) ? 0 : base[n0];
    const int hi = (n1 >= N) ? E : base[n1];
    const int p0 = lo + blockIdx.x * 64;
    if (p0 >= hi) return;

    for (int i = tid; i < 640; i += 256) w1_l[i] = Wfc1[i];
    {
        const size_t emax = (size_t)E * 10 - 1;
        for (int i = tid; i < 640; i += 256) {
            size_t idx = (size_t)p0 * 10 + i;
            esc_l[i] = esc_ord[idx > emax ? emax : idx];
        }
    }
    __syncthreads();
    {
        const int r = tid >> 2, c0 = (tid & 3) << 4;
        float hval[16];
        #pragma unroll
        for (int c = 0; c < 16; c++) {
            float acc = 0.f;
            #pragma unroll
            for (int q = 0; q < 10; q++) acc += esc_l[r * 10 + q] * w1_l[q * 64 + c0 + c];
            acc *= INV_SQRT10;
            hval[c] = acc / (1.f + __expf(-acc));
        }
        unsigned pk[8];
        #pragma unroll
        for (int j = 0; j < 8; j++)
            pk[j] = (unsigned)f2bf(hval[2 * j]) | ((unsigned)f2bf(hval[2 * j + 1]) << 16);
        const int swz = (r & 7) << 4;
        const int b0 = (r << 7) + (c0 << 1);
        *(uint4*)(hb + (b0 ^ swz)) = make_uint4(pk[0], pk[1], pk[2], pk[3]);
        *(uint4*)(hb + ((b0 + 16) ^ swz)) = make_uint4(pk[4], pk[5], pk[6], pk[7]);
    }
    __syncthreads();
    const int wv = tid >> 6, lane = tid & 63;
    const int mrow = lane & 15, kgrp = lane >> 4;
    f32x4 acc[12];
    #pragma unroll
    for (int t = 0; t < 12; t++) acc[t] = (f32x4){0.f, 0.f, 0.f, 0.f};
    #pragma unroll
    for (int kc = 0; kc < 2; kc++) {
        const int r = wv * 16 + mrow;
        const int abyte = ((r << 7) + (kc << 6) + (kgrp << 4)) ^ ((r & 7) << 4);
        const bf16x8 afrag = *(const bf16x8*)(hb + abyte);
        #pragma unroll
        for (int t = 0; t < 12; t++) {
            const int c = t * 16 + mrow;
            const bf16x8 bfrag = *(const bf16x8*)(wfb + c * 64 + kc * 32 + kgrp * 8);
            acc[t] = __builtin_amdgcn_mfma_f32_16x16x32_bf16(afrag, bfrag, acc[t], 0, 0, 0);
        }
    }
    #pragma unroll
    for (int rg = 0; rg < 4; rg++) {
        const int rloc = wv * 16 + kgrp * 4 + rg;
        const int pos = p0 + rloc;
        if (pos < hi && (pos - lo) < cap) {
            #pragma unroll
            for (int tb = 0; tb < 4; tb++) {
                const int c = tb * 16 + mrow;
                const unsigned p12 = (unsigned)f2bf(acc[tb][rg] * INV_SQRT64)
                                   | ((unsigned)f2bf(acc[tb + 4][rg] * INV_SQRT64) << 16);
                wbuf12[(size_t)(pos - lo) * 64 + c] = p12;
                wbufB[(size_t)(pos - lo) * 64 + c] = f2bf(acc[tb + 8][rg] * INV_SQRT64);
            }
        }
    }
}

// ---------------------------------------------------------------------------
// K2b: aggregation only. wave-per-dst-node over CSR; writes deg-normalized
//   Msb (N x 96 bf16) and Mvb ((n*3+i) x 96 bf16).
// ---------------------------------------------------------------------------
__global__ __launch_bounds__(256) void k_agg(
    const unsigned short* __restrict__ hsb, const unsigned short* __restrict__ hvbb,
    const int* __restrict__ src_ord, const float4* __restrict__ sh_ord,
    const int* __restrict__ base, const int* __restrict__ cnt,
    const unsigned* __restrict__ wbuf12, const unsigned short* __restrict__ wbufB,
    unsigned short* __restrict__ Msb, unsigned short* __restrict__ Mvb,
    int n0, int n1, int N, int E)
{
    const int wave = threadIdx.x >> 6, lane = threadIdx.x & 63;
    const int n = n0 + blockIdx.x * 4 + wave;
    if (n >= n1) return;
    const int lo = (n0 == 0) ? 0 : base[n0];

    float aS = 0.f, aSB = 0.f;
    float aV0 = 0.f, aV1 = 0.f, aV2 = 0.f;
    float aB0 = 0.f, aB1 = 0.f, aB2 = 0.f;
    const int b0 = base[n];
    const int c_ = cnt[n];
    const size_t wb = (size_t)(b0 - lo) * 64;
    int s_nx = (c_ > 0) ? src_ord[b0] : 0;
    for (int j = 0; j < c_; ++j) {
        const int s = s_nx;
        if (j + 1 < c_) s_nx = src_ord[b0 + j + 1];
        const unsigned p12 = wbuf12[wb + (size_t)j * 64 + lane];
        const float w1 = bf2f((unsigned short)(p12 & 0xFFFF));
        const float w2 = bf2f((unsigned short)(p12 >> 16));
        const float wB = bf2f(wbufB[wb + (size_t)j * 64 + lane]);
        const float gs = bf2f(hsb[(size_t)s * 64 + lane]);
        float gv0 = 0.f, gv1 = 0.f, gv2 = 0.f;
        if (lane < 32) {
            gv0 = bf2f(hvbb[(size_t)s * 96 + lane]);
            gv1 = bf2f(hvbb[(size_t)s * 96 + 32 + lane]);
            gv2 = bf2f(hvbb[(size_t)s * 96 + 64 + lane]);
        }
        const float4 s4 = sh_ord[b0 + j];
        const float gvdot = gv0 * s4.y + gv1 * s4.z + gv2 * s4.w;
        const float gvd = __shfl(gvdot, lane & 31);
        aS  += gs * s4.x * w1;
        aSB += gvd * INV_SQRT3 * wB;
        aV0 += gs * s4.y * w2;
        aV1 += gs * s4.z * w2;
        aV2 += gs * s4.w * w2;
        aB0 += gv0 * s4.x * wB;
        aB1 += gv1 * s4.x * wB;
        aB2 += gv2 * s4.x * wB;
    }
    const float invd = 1.f / (float)max(c_, 1);
    unsigned short* msp = Msb + (size_t)n * 96;
    unsigned short* mvp = Mvb + (size_t)n * 3 * 96;
    msp[lane] = f2bf(aS * invd);
    if (lane >= 32) msp[64 + (lane - 32)] = f2bf(aSB * invd);
    mvp[0 * 96 + lane] = f2bf(aV0 * invd);
    mvp[1 * 96 + lane] = f2bf(aV1 * invd);
    mvp[2 * 96 + lane] = f2bf(aV2 * invd);
    if (lane < 32) {
        mvp[0 * 96 + 64 + lane] = f2bf(aB0 * invd);
        mvp[1 * 96 + 64 + lane] = f2bf(aB1 * invd);
        mvp[2 * 96 + 64 + lane] = f2bf(aB2 * invd);
    }
}

// ---------------------------------------------------------------------------
// K3: node finalize as MFMA. 64 nodes/block, 4 waves.
//   GEMM1: Msb(64,96) @ wob(96, OS+1 padded)  -> s cols + alpha (col OS)
//   GEMM2: Mvb(192,96) @ wv2b(96,32)          -> ov; rows = nloc*3+i
//   epilogue: s = scs + alpha*os ; v = scv + alpha*ov ; gate/silu or final out
// ---------------------------------------------------------------------------
template <int OS, bool FINAL>
__global__ __launch_bounds__(256) void k_node_out(
    const unsigned short* __restrict__ Msb, const unsigned short* __restrict__ Mvb,
    const float* __restrict__ attr,
    const float* __restrict__ scs, const float* __restrict__ scv,
    const unsigned short* __restrict__ wob, const unsigned short* __restrict__ wv2b,
    float* __restrict__ outF,
    unsigned short* __restrict__ outSb, unsigned short* __restrict__ outVb, int N)
{
    constexpr int CT1 = (OS + 16 + 15) / 16;   // 7 (OS=96) / 5 (OS=64)
    constexpr int TA = OS / 16;                // tile holding alpha col (mrow==0)
    __shared__ float attr_l[64];
    __shared__ float alpha_l[64];
    __shared__ float gate_l[64][32];
    const int tid = threadIdx.x;
    const int n0 = blockIdx.x * 64;
    if (tid < 64) attr_l[tid] = (n0 + tid < N) ? attr[n0 + tid] : 0.f;
    __syncthreads();
    const int wv = tid >> 6, lane = tid & 63;
    const int mrow = lane & 15, kg = lane >> 4;

    // ---- GEMM1
    const int rbase = wv * 16;
    const int rc = min(n0 + rbase + mrow, N - 1);
    f32x4 acc[CT1];
    #pragma unroll
    for (int t = 0; t < CT1; t++) acc[t] = (f32x4){0.f, 0.f, 0.f, 0.f};
    #pragma unroll
    for (int kc = 0; kc < 3; kc++) {
        const bf16x8 a = *(const bf16x8*)(Msb + (size_t)rc * 96 + kc * 32 + kg * 8);
        #pragma unroll
        for (int t = 0; t < CT1; t++) {
            const bf16x8 b = *(const bf16x8*)(wob + (size_t)(t * 16 + mrow) * 96 + kc * 32 + kg * 8);
            acc[t] = __builtin_amdgcn_mfma_f32_16x16x32_bf16(a, b, acc[t], 0, 0, 0);
        }
    }
    if (mrow == 0) {
        #pragma unroll
        for (int rg = 0; rg < 4; rg++) {
            const int row = rbase + kg * 4 + rg;
            alpha_l[row] = acc[TA][rg] * INV_SQRT96 * attr_l[row];
        }
    }
    __syncthreads();
    // ---- epilogue 1
    #pragma unroll
    for (int t = 0; t < CT1; t++) {
        const int c = t * 16 + mrow;
        if (c < OS) {
            #pragma unroll
            for (int rg = 0; rg < 4; rg++) {
                const int row = rbase + kg * 4 + rg;
                const int n = n0 + row;
                if (n < N) {
                    const float os = acc[t][rg] * INV_SQRT96 * attr_l[row];
                    const float s = scs[(size_t)n * OS + c] + alpha_l[row] * os;
                    if (FINAL) {
                        outF[(size_t)n * 160 + c] = s;
                    } else {
                        if (c < 64) outSb[(size_t)n * 64 + c] = f2bf(s / (1.f + __expf(-s)));
                        else        gate_l[row][c - 64] = 1.f / (1.f + __expf(-s));
                    }
                }
            }
        }
    }
    __syncthreads();
    // ---- GEMM2: rows rv = nloc*3+i (192), wave handles 3 row-tiles
    #pragma unroll
    for (int j = 0; j < 3; j++) {
        const int rb2 = (wv * 3 + j) * 16;
        const int rv = rb2 + mrow;
        const int nl = rv / 3, ii = rv - nl * 3;
        const int nc2 = min(n0 + nl, N - 1);
        f32x4 acc2[2];
        acc2[0] = (f32x4){0.f, 0.f, 0.f, 0.f};
        acc2[1] = (f32x4){0.f, 0.f, 0.f, 0.f};
        #pragma unroll
        for (int kc = 0; kc < 3; kc++) {
            const bf16x8 a = *(const bf16x8*)(Mvb + ((size_t)nc2 * 3 + ii) * 96 + kc * 32 + kg * 8);
            #pragma unroll
            for (int t = 0; t < 2; t++) {
                const bf16x8 b = *(const bf16x8*)(wv2b + (size_t)(t * 16 + mrow) * 96 + kc * 32 + kg * 8);
                acc2[t] = __builtin_amdgcn_mfma_f32_16x16x32_bf16(a, b, acc2[t], 0, 0, 0);
            }
        }
        #pragma unroll
        for (int t = 0; t < 2; t++) {
            const int k = t * 16 + mrow;
            #pragma unroll
            for (int rg = 0; rg < 4; rg++) {
                const int rv2 = rb2 + kg * 4 + rg;
                const int nl2 = rv2 / 3, i2 = rv2 - nl2 * 3;
                const int n = n0 + nl2;
                if (n < N) {
                    const float ov = acc2[t][rg] * INV_SQRT96 * attr_l[nl2];
                    const float v = scv[(size_t)n * 96 + i2 * 32 + k] + alpha_l[nl2] * ov;
                    if (FINAL) outF[(size_t)n * 160 + 64 + k * 3 + i2] = v;
                    else       outVb[(size_t)n * 96 + i2 * 32 + k] = f2bf(v * gate_l[nl2][k]);
                }
            }
        }
    }
}

// ---------------------------------------------------------------------------
extern "C" void kernel_launch(void* const* d_in, const int* in_sizes, int n_in,
                              void* d_out, int out_size, void* d_ws, size_t ws_size,
                              hipStream_t stream)
{
    const float* node_s = (const float*)d_in[0];
    const float* node_v = (const float*)d_in[1];
    const float* attr   = (const float*)d_in[2];
    const int*   esrc   = (const int*)d_in[3];
    const int*   edst   = (const int*)d_in[4];
    const float* esh    = (const float*)d_in[5];
    const float* esc    = (const float*)d_in[6];
    const float* W[18];
    for (int i = 0; i < 18; i++) W[i] = (const float*)d_in[7 + i];
    // per layer: 0 sc_s, 1 sc_v, 2 lin1_s, 3 lin1_v, 4 fc1, 5 fc2, 6 lin2_s, 7 lin2_v, 8 alpha

    const int N = in_sizes[0] / 64;
    const int E = in_sizes[3];
    const int NB = (N + 255) / 256;

    char* p = (char*)d_ws;
    unsigned short* xsb  = (unsigned short*)p; p += (size_t)N * 64 * 2;
    unsigned short* xvpb = (unsigned short*)p; p += (size_t)N * 96 * 2;
    unsigned short* hsb  = (unsigned short*)p; p += (size_t)N * 64 * 2;
    unsigned short* hvbb = (unsigned short*)p; p += (size_t)N * 96 * 2;
    unsigned short* Msb  = (unsigned short*)p; p += (size_t)N * 96 * 2;
    unsigned short* Mvb  = (unsigned short*)p; p += (size_t)N * 288 * 2;
    float* scs = (float*)p; p += (size_t)N * 96 * 4;
    float* scv = (float*)p; p += (size_t)N * 96 * 4;
    unsigned short* wsb1 = (unsigned short*)p; p += 160 * 64 * 2;
    unsigned short* wsb2 = (unsigned short*)p; p += 128 * 64 * 2;
    unsigned short* wvb1 = (unsigned short*)p; p += 64 * 32 * 2;
    unsigned short* wvb2 = (unsigned short*)p; p += 64 * 32 * 2;
    unsigned short* wfb1 = (unsigned short*)p; p += 192 * 64 * 2;
    unsigned short* wfb2 = (unsigned short*)p; p += 192 * 64 * 2;
    unsigned short* wob1 = (unsigned short*)p; p += 112 * 96 * 2;
    unsigned short* wob2 = (unsigned short*)p; p += 80 * 96 * 2;
    unsigned short* wv2b1 = (unsigned short*)p; p += 32 * 96 * 2;
    unsigned short* wv2b2 = (unsigned short*)p; p += 32 * 96 * 2;
    int* cnt    = (int*)p; p += (size_t)N * 4;
    int* cursor = (int*)p; p += (size_t)N * 4;
    int* basei  = (int*)p; p += (size_t)N * 4;
    int* partial = (int*)p; p += (size_t)NB * 4;
    p = (char*)(((size_t)p + 255) & ~(size_t)255);
    int* src_ord = (int*)p; p += (size_t)E * 4;
    p = (char*)(((size_t)p + 15) & ~(size_t)15);
    float4* sh_ord = (float4*)p; p += (size_t)E * 16;
    float* esc_ord = (float*)p; p += (size_t)E * 40;
    p = (char*)(((size_t)p + 255) & ~(size_t)255);
    const size_t used_fixed = (size_t)(p - (char*)d_ws);

    // adaptive: pick smallest NQ whose wbuf fits
    int NQ = 4;
    size_t cap = 0;
    {
        const int cands[3] = {1, 2, 4};
        for (int ci = 0; ci < 3; ci++) {
            const int c = cands[ci];
            size_t cc = (c == 1) ? (size_t)E : ((size_t)E / c) * 9 / 8 + 256;
            if (used_fixed + cc * 384 <= ws_size) { NQ = c; cap = cc; break; }
        }
        if (cap == 0) { NQ = 4; cap = ((size_t)E / 4) * 9 / 8 + 256; }
    }
    unsigned* wbuf12      = (unsigned*)p;       p += cap * 256;
    unsigned short* wbufB = (unsigned short*)p; p += cap * 128;

    const int nb  = (N + 63) / 64;
    const int ebk = (E + 255) / 256;
    const int Q   = (N + NQ - 1) / NQ;
    const int qb  = (Q + 3) / 4;
    const int emb = (int)((cap + 63) / 64);

    // ---- prep + CSR build
    hipMemsetAsync(cnt, 0, (size_t)2 * N * sizeof(int), stream);  // cnt + cursor
    k_prep_nodes<<<2048, 256, 0, stream>>>(node_s, node_v, edst, xsb, xvpb, cnt, N, E);
    k_prep_w<96><<<32, 256, 0, stream>>>(W[2], W[0], W[3], W[1], W[5], W[6], W[7], W[8],
                                         wsb1, wvb1, wfb1, wob1, wv2b1);
    k_prep_w<64><<<32, 256, 0, stream>>>(W[11], W[9], W[12], W[10], W[14], W[15], W[16], W[17],
                                         wsb2, wvb2, wfb2, wob2, wv2b2);
    k_scan1<<<NB, 256, 0, stream>>>(cnt, partial, N);
    k_scan2<<<1, 1024, 0, stream>>>(partial, NB);
    k_scan3<<<NB, 256, 0, stream>>>(cnt, partial, basei, N);
    k_scatter<<<ebk, 256, 0, stream>>>(esrc, edst, esh, esc, basei, cursor,
                                       src_ord, sh_ord, esc_ord, E);

    // ---- layer 1
    k_node_mfma<96><<<nb, 256, 0, stream>>>(xsb, xvpb, attr, wsb1, wvb1,
                                            hsb, hvbb, scs, scv, N);
    for (int q = 0; q < NQ; q++) {
        const int n0 = q * Q, n1 = min(N, (q + 1) * Q);
        if (n0 >= n1) break;
        k_edge_mlp<<<emb, 256, 0, stream>>>(esc_ord, basei, W[4], wfb1,
                                            wbuf12, wbufB, n0, n1, N, E, (int)cap);
        k_agg<<<qb, 256, 0, stream>>>(hsb, hvbb, src_ord, sh_ord, basei, cnt,
                                      wbuf12, wbufB, Msb, Mvb, n0, n1, N, E);
    }
    k_node_out<96, false><<<nb, 256, 0, stream>>>(Msb, Mvb, attr, scs, scv,
                                                  wob1, wv2b1,
                                                  nullptr, xsb, xvpb, N);
    // ---- layer 2
    k_node_mfma<64><<<nb, 256, 0, stream>>>(xsb, xvpb, attr, wsb2, wvb2,
                                            hsb, hvbb, scs, scv, N);
    for (int q = 0; q < NQ; q++) {
        const int n0 = q * Q, n1 = min(N, (q + 1) * Q);
        if (n0 >= n1) break;
        k_edge_mlp<<<emb, 256, 0, stream>>>(esc_ord, basei, W[13], wfb2,
                                            wbuf12, wbufB, n0, n1, N, E, (int)cap);
        k_agg<<<qb, 256, 0, stream>>>(hsb, hvbb, src_ord, sh_ord, basei, cnt,
                                      wbuf12, wbufB, Msb, Mvb, n0, n1, N, E);
    }
    k_node_out<64, true><<<nb, 256, 0, stream>>>(Msb, Mvb, attr, scs, scv,
                                                 wob2, wv2b2,
                                                 (float*)d_out, nullptr, nullptr, N);
}